// Round 1
// 678.229 us; speedup vs baseline: 1.6135x; 1.6135x over previous
//
#include <hip/hip_runtime.h>

typedef unsigned short u16;
typedef unsigned int u32;

__device__ __forceinline__ float b2f(u16 v) { return __uint_as_float((u32)v << 16); }
__device__ __forceinline__ float lopart(u32 u) { return __uint_as_float(u << 16); }
__device__ __forceinline__ float hipart(u32 u) { return __uint_as_float(u & 0xffff0000u); }
__device__ __forceinline__ u16 f2b(float f) {
  u32 u = __float_as_uint(f);
  u32 r = u + 0x7fffu + ((u >> 16) & 1u);
  return (u16)(r >> 16);
}
__device__ __forceinline__ u32 pk2(float a, float b) {
  return (u32)f2b(a) | ((u32)f2b(b) << 16);
}

struct Ptrs { const void* p[29]; };

typedef __attribute__((ext_vector_type(8))) short short8;
typedef __attribute__((ext_vector_type(4))) float floatx4;

// ---------------- K-2: dtype flag (bn1_g[0]: bf16 pair 0x3F803F80 vs fp32 0x3F800000) ----------------
__global__ void k_resolve(const void* __restrict__ g1, int* __restrict__ dtf) {
  if (threadIdx.x == 0) {
    u32 w = *(const u32*)g1;
    *dtf = ((w & 0xffffu) != 0) ? 1 : 0;
  }
}

// ---------------- K-1: convert A + all weights to fp32 (C-order identity; dict order) ----------------
__global__ __launch_bounds__(256) void k_cvt(Ptrs ps, const int* __restrict__ dtf,
                                             float* __restrict__ Af, float* __restrict__ Wf) {
  bool BF = *dtf != 0;
  int i = blockIdx.x * 256 + threadIdx.x;
  if (i < 250000) {
    const void* pA = ps.p[1];
    Af[i] = BF ? b2f(((const u16*)pA)[i]) : ((const float*)pA)[i];
    return;
  }
  int j = i - 250000;
  if (j >= 65322) return;
  const int SZ[27] = {1024,32,2048,64,12288,64,12288,64,4096,64,4096,64,2048,32,
                      10240,64,60,6,32,500,16000,36,36,6,6,32,32};
  int t = 0, off = 0;
#pragma unroll
  for (int k = 0; k < 27; ++k) {
    if (t == k && j >= off + SZ[k]) { off += SZ[k]; t = k + 1; }
  }
  const void* src = ps.p[2 + t];
  int l = j - off;
  Wf[j] = BF ? b2f(((const u16*)src)[l]) : ((const float*)src)[l];
}

// ---------------- K-0b: x -> fp32 (identity C-order) ----------------
__global__ __launch_bounds__(256) void k_cvtx(const void* __restrict__ x, const int* __restrict__ dtf,
                                              float* __restrict__ xf) {
  bool BF = *dtf != 0;
  int i = blockIdx.x * 256 + threadIdx.x;
  if (i < 2560000) xf[i] = BF ? b2f(((const u16*)x)[i]) : ((const float*)x)[i];
}

// ---------------- K0: A2 = A @ A  (fp32) ----------------
__global__ __launch_bounds__(256) void k_a2(const float* __restrict__ Af, float* __restrict__ A2) {
  __shared__ float Arow[8][500];
  int tid = threadIdx.x;
  int j = blockIdx.x * 256 + tid;
  int i0 = blockIdx.y * 8;
  for (int i = tid; i < 4000; i += 256) {
    int r = i / 500, kk = i - r * 500;
    int ii = i0 + r; if (ii > 499) ii = 499;
    Arow[r][kk] = Af[ii * 500 + kk];
  }
  __syncthreads();
  if (j >= 500) return;
  float acc[8];
#pragma unroll
  for (int ii = 0; ii < 8; ++ii) acc[ii] = 0.f;
  for (int k = 0; k < 500; ++k) {
    float akj = Af[k * 500 + j];
#pragma unroll
    for (int ii = 0; ii < 8; ++ii) acc[ii] += Arow[ii][k] * akj;
  }
#pragma unroll
  for (int ii = 0; ii < 8; ++ii)
    if (i0 + ii < 500) A2[(i0 + ii) * 500 + j] = acc[ii];
}

// ---------------- K0b: pack A, A2 to zero-padded 512x512 bf16 ----------------
__global__ __launch_bounds__(256) void k_pk(const float* __restrict__ Af, const float* __restrict__ A2,
                                            u16* __restrict__ Abf, u16* __restrict__ A2bf) {
  int i = blockIdx.x * 256 + threadIdx.x;
  if (i >= 262144) return;
  int r = i >> 9, v = i & 511;
  bool in = (r < 500) && (v < 500);
  Abf[i]  = f2b(in ? Af[r * 500 + v] : 0.f);
  A2bf[i] = f2b(in ? A2[r * 500 + v] : 0.f);
}

// ---------------- K0c: transpose frontend weights into [k][o] layouts (coalesced per-lane reads) ----
// WT float layout:
//   te1T [0,2048)     : [c*64+o]         = te1W[o*32+c]
//   c1T  [2048,3072)  : [i*32+c]         = c1W[c*32+i]
//   qkT  [3072,15360) : u32 [(i*3+tap)*64+o] = pack(qW[o,i,tap], kW[o,i,tap]) as bf16 pair
//   lvT  [15360,19456): [i*64+o]         = lvW[o*64+i]
//   loT  [19456,23552): [j*64+o]         = loW[o*64+j]
//   te2T [23552,25600): [j*32+c]         = te2W[c*64+j]
__global__ __launch_bounds__(256) void k_wprep(const float* __restrict__ Wf, float* __restrict__ WT) {
  int i = blockIdx.x * 256 + threadIdx.x;
  if (i < 2048) {
    int c = i >> 6, o = i & 63;
    WT[i] = Wf[1056 + o * 32 + c];
  } else if (i < 3072) {
    int j = i - 2048; int ii = j >> 5, c = j & 31;
    WT[i] = Wf[c * 32 + ii];
  } else if (i < 15360) {
    int j = i - 3072;
    int o = j & 63, it = j >> 6; int ii = it / 3, tap = it - ii * 3;
    int si = o * 192 + ii * 3 + tap;
    ((u32*)WT)[i] = pk2(Wf[3168 + si], Wf[15520 + si]);
  } else if (i < 19456) {
    int j = i - 15360; int ii = j >> 6, o = j & 63;
    WT[i] = Wf[27872 + o * 64 + ii];
  } else if (i < 23552) {
    int j = i - 19456; int jj = j >> 6, o = j & 63;
    WT[i] = Wf[32032 + o * 64 + jj];
  } else if (i < 25600) {
    int j = i - 23552; int jj = j >> 5, c = j & 31;
    WT[i] = Wf[36192 + c * 64 + jj];
  }
}

// ---------------- K1: frontend, one (b,n) pair per WAVE, zero block barriers ----------------
// lane = output channel (64). Per-wave LDS arena (2368 floats, 16B aligned rows of 12):
//   phase          writes              reads
//   x load         x   [0,384)
//   residual                           x
//   h1             h1  [384,1152)      x
//   qkv (regs)                         h1 (broadcast b128)
//   q/k spill      q[0,768) k[768,1536)
//   scores+smax    P   [1536,2336)     q,k
//   PV (regs)                          P (+ v in regs)
//   o spill        o   [0,768)
//   lino           lo  [768,1536)      o (broadcast)
//   te2 + store                        lo
// In-order per-wave LDS + wave_barrier (compile-time fence) replaces __syncthreads.
__global__ __launch_bounds__(256, 4) void k_front2(
    const float* __restrict__ xf, const float* __restrict__ WT,
    const float* __restrict__ c1B, const float* __restrict__ te1B,
    const float* __restrict__ qB, const float* __restrict__ kB,
    const float* __restrict__ lvB, const float* __restrict__ loB,
    const float* __restrict__ te2B,
    float* __restrict__ h3x, float* __restrict__ res6)
{
  __shared__ __align__(16) float arena[4][2368];
  int tid = threadIdx.x;
  int wave = tid >> 6, lane = tid & 63;
  float* Aw = arena[wave];
  int pair = blockIdx.x * 4 + wave;
  int b = pair / 500, n = pair - b * 500;

  const float* te1T = WT;
  const float* c1T  = WT + 2048;
  const u32*   qkT  = (const u32*)(WT + 3072);
  const float* lvT  = WT + 15360;
  const float* loT  = WT + 19456;
  const float* te2T = WT + 23552;

  // ---- x -> LDS rows [c*12 + t]
  {
    int c0 = lane >> 1, hf = (lane & 1) * 5;
    const float* xp = xf + ((b * 32 + c0) * 500 + n) * 10 + hf;
    float* dst = Aw + c0 * 12 + hf;
#pragma unroll
    for (int k2 = 0; k2 < 5; ++k2) dst[k2] = xp[k2];
  }
  __builtin_amdgcn_wave_barrier();

  int cl = lane & 31, th = lane >> 5;

  // ---- residual: lane=(c, th), 3 time outputs each
  {
    float r0 = c1B[cl], r1 = r0, r2 = r0;
#pragma unroll 4
    for (int i = 0; i < 32; ++i) {
      float w = c1T[i * 32 + cl];
      const float* xr = Aw + i * 12 + 4 + th * 3;
      r0 += w * xr[0]; r1 += w * xr[1]; r2 += w * xr[2];
    }
    float* rp = res6 + ((b * 32 + cl) * 500 + n) * 6 + th * 3;
    rp[0] = r0; rp[1] = r1; rp[2] = r2;
  }

  // ---- h1: lane = out channel o, 10 t's in regs
  {
    float bb = te1B[lane];
    float h1r[10];
#pragma unroll
    for (int t = 0; t < 10; ++t) h1r[t] = bb;
#pragma unroll 4
    for (int c = 0; c < 32; ++c) {
      float w = te1T[c * 64 + lane];
      const float* xr = Aw + c * 12;
      float4 xa = *(const float4*)xr;
      float4 xb = *(const float4*)(xr + 4);
      float2 xc = *(const float2*)(xr + 8);
      h1r[0] += w * xa.x; h1r[1] += w * xa.y; h1r[2] += w * xa.z; h1r[3] += w * xa.w;
      h1r[4] += w * xb.x; h1r[5] += w * xb.y; h1r[6] += w * xb.z; h1r[7] += w * xb.w;
      h1r[8] += w * xc.x; h1r[9] += w * xc.y;
    }
    float* hp = Aw + 384 + lane * 12;
    *(float4*)hp       = make_float4(h1r[0], h1r[1], h1r[2], h1r[3]);
    *(float4*)(hp + 4) = make_float4(h1r[4], h1r[5], h1r[6], h1r[7]);
    *(float2*)(hp + 8) = make_float2(h1r[8], h1r[9]);
  }
  __builtin_amdgcn_wave_barrier();

  // ---- q,k,v: lane = o; 66 FMA per i-iteration, broadcast h1 rows
  float qr[10], kr[10], vr[10];
  {
    float bq = qB[lane], bk = kB[lane], bv = lvB[lane];
#pragma unroll
    for (int t = 0; t < 10; ++t) { qr[t] = bq; kr[t] = bk; vr[t] = bv; }
    const u32* qp0 = qkT + lane;
    const float* lp0 = lvT + lane;
#pragma unroll 2
    for (int i = 0; i < 64; ++i) {
      const float* hp2 = Aw + 384 + i * 12;
      float4 ha = *(const float4*)hp2;
      float4 hb = *(const float4*)(hp2 + 4);
      float2 hc = *(const float2*)(hp2 + 8);
      u32 u0 = qp0[i * 192];
      u32 u1 = qp0[i * 192 + 64];
      u32 u2 = qp0[i * 192 + 128];
      float wv = lp0[i * 64];
      float q0 = lopart(u0), q1 = lopart(u1), q2 = lopart(u2);
      float k0 = hipart(u0), k1 = hipart(u1), k2 = hipart(u2);
      float hh[10] = {ha.x, ha.y, ha.z, ha.w, hb.x, hb.y, hb.z, hb.w, hc.x, hc.y};
#pragma unroll
      for (int t = 0; t < 10; ++t) { float c_ = hh[t]; qr[t] += q1 * c_; kr[t] += k1 * c_; vr[t] += wv * c_; }
#pragma unroll
      for (int t = 1; t < 10; ++t) { float c_ = hh[t - 1]; qr[t] += q0 * c_; kr[t] += k0 * c_; }
#pragma unroll
      for (int t = 0; t < 9; ++t) { float c_ = hh[t + 1]; qr[t] += q2 * c_; kr[t] += k2 * c_; }
    }
  }
  // spill q,k (v stays in regs for PV)
  {
    float* qp = Aw + lane * 12;
    *(float4*)qp       = make_float4(qr[0], qr[1], qr[2], qr[3]);
    *(float4*)(qp + 4) = make_float4(qr[4], qr[5], qr[6], qr[7]);
    *(float2*)(qp + 8) = make_float2(qr[8], qr[9]);
    float* kp = Aw + 768 + lane * 12;
    *(float4*)kp       = make_float4(kr[0], kr[1], kr[2], kr[3]);
    *(float4*)(kp + 4) = make_float4(kr[4], kr[5], kr[6], kr[7]);
    *(float2*)(kp + 8) = make_float2(kr[8], kr[9]);
  }
  __builtin_amdgcn_wave_barrier();

  // ---- scores + softmax: 80 (head,row) rows over 2 passes
  {
#pragma unroll
    for (int pass = 0; pass < 2; ++pass) {
      int row = pass * 64 + lane;
      if (row < 80) {
        int h8 = (row / 10) * 8, r = row - (row / 10) * 10;
        float sv[10];
#pragma unroll
        for (int s = 0; s < 10; ++s) sv[s] = 0.f;
#pragma unroll 2
        for (int d = 0; d < 8; ++d) {
          int jj = h8 + d;
          float qv = Aw[jj * 12 + r];
          const float* kp2 = Aw + 768 + jj * 12;
          float4 ka = *(const float4*)kp2;
          float4 kb = *(const float4*)(kp2 + 4);
          float2 kc = *(const float2*)(kp2 + 8);
          sv[0] += qv * ka.x; sv[1] += qv * ka.y; sv[2] += qv * ka.z; sv[3] += qv * ka.w;
          sv[4] += qv * kb.x; sv[5] += qv * kb.y; sv[6] += qv * kb.z; sv[7] += qv * kb.w;
          sv[8] += qv * kc.x; sv[9] += qv * kc.y;
        }
        const float sc_ = 0.35355339059327373f;
        float mx = sv[0];
#pragma unroll
        for (int s = 1; s < 10; ++s) mx = fmaxf(mx, sv[s]);
        float tot = 0.f, ev[10];
#pragma unroll
        for (int s = 0; s < 10; ++s) { ev[s] = expf((sv[s] - mx) * sc_); tot += ev[s]; }
        float inv = 1.f / tot;
        float* pp = Aw + 1536 + row * 10;
#pragma unroll
        for (int s = 0; s < 10; ++s) pp[s] = ev[s] * inv;
      }
    }
  }
  __builtin_amdgcn_wave_barrier();

  // ---- PV: lane = j (head h=j>>3), v in regs, P broadcast per 8-lane group
  float orr[10];
  {
    const float* pb = Aw + 1536 + (lane >> 3) * 100;
#pragma unroll
    for (int t = 0; t < 10; ++t) {
      const float* pr = pb + t * 10;
      float a = 0.f;
#pragma unroll
      for (int s = 0; s < 10; ++s) a += pr[s] * vr[s];
      orr[t] = a;
    }
    float* op = Aw + lane * 12;   // overwrites q (dead)
    *(float4*)op       = make_float4(orr[0], orr[1], orr[2], orr[3]);
    *(float4*)(op + 4) = make_float4(orr[4], orr[5], orr[6], orr[7]);
    *(float2*)(op + 8) = make_float2(orr[8], orr[9]);
  }
  __builtin_amdgcn_wave_barrier();

  // ---- lino: lane = o
  {
    float bo = loB[lane];
    float lor[10];
#pragma unroll
    for (int t = 0; t < 10; ++t) lor[t] = bo;
    const float* lp0 = loT + lane;
#pragma unroll 2
    for (int j = 0; j < 64; ++j) {
      float w = lp0[j * 64];
      const float* op2 = Aw + j * 12;
      float4 oa = *(const float4*)op2;
      float4 ob = *(const float4*)(op2 + 4);
      float2 oc = *(const float2*)(op2 + 8);
      lor[0] += w * oa.x; lor[1] += w * oa.y; lor[2] += w * oa.z; lor[3] += w * oa.w;
      lor[4] += w * ob.x; lor[5] += w * ob.y; lor[6] += w * ob.z; lor[7] += w * ob.w;
      lor[8] += w * oc.x; lor[9] += w * oc.y;
    }
    float* sp = Aw + 768 + lane * 12;   // overwrites k (dead)
    *(float4*)sp       = make_float4(lor[0], lor[1], lor[2], lor[3]);
    *(float4*)(sp + 4) = make_float4(lor[4], lor[5], lor[6], lor[7]);
    *(float2*)(sp + 8) = make_float2(lor[8], lor[9]);
  }
  __builtin_amdgcn_wave_barrier();

  // ---- te2 + h3x store: lane = (c, th), 5 t's each
  {
    float bt2 = te2B[cl];
    float a5[5];
#pragma unroll
    for (int k2 = 0; k2 < 5; ++k2) a5[k2] = bt2;
    const float* tp0 = te2T + cl;
    const float* base = Aw + 768 + th * 5;
#pragma unroll 2
    for (int j = 0; j < 64; ++j) {
      float w = tp0[j * 32];
      const float* lp = base + j * 12;
#pragma unroll
      for (int k2 = 0; k2 < 5; ++k2) a5[k2] += w * lp[k2];
    }
    int t0 = th * 5;
#pragma unroll
    for (int k2 = 0; k2 < 5; ++k2)
      h3x[((b * 10 + t0 + k2) * 500 + n) * 32 + cl] = a5[k2];
  }
}

// ---------------- K2: MFMA z1 = A @ XT, z2 = A2 @ XT ----------------
__global__ __launch_bounds__(256, 4) void k_z12m(const float* __restrict__ h3x,
    const u16* __restrict__ Abf, const u16* __restrict__ A2bf,
    float* __restrict__ z1x, float* __restrict__ z2x) {
  __shared__ u32 xlsT[8192];     // [n][half-row] pairs, swizzled (32 KB)
  int tid = threadIdx.x, bt = blockIdx.x;
  const float* src = h3x + bt * 16000;
  for (int i = tid; i < 8192; i += 256) {
    int n = i & 31, h = i >> 5;
    int r0 = 2 * h;
    float v0 = (r0 < 500) ? src[r0 * 32 + n] : 0.f;
    float v1 = (r0 + 1 < 500) ? src[(r0 + 1) * 32 + n] : 0.f;
    xlsT[n * 256 + (((h & 0xFC) ^ ((n & 15) << 2)) | (h & 3))] = pk2(v0, v1);
  }
  __syncthreads();
  int lane = tid & 63, wave = tid >> 6;
  int q = lane >> 4, ln = lane & 15;
  int rbase = blockIdx.y * 64 + wave * 16;
  const u32* Au = (const u32*)Abf;
  const u32* A2u = (const u32*)A2bf;
  int arow = (rbase + ln) * 256;
  union F8 { u32 u[4]; short8 s; };
  floatx4 acc1[2] = {{0.f,0.f,0.f,0.f},{0.f,0.f,0.f,0.f}};
  floatx4 acc2[2] = {{0.f,0.f,0.f,0.f},{0.f,0.f,0.f,0.f}};
  for (int c2 = 0; c2 < 16; ++c2) {
    int hb = c2 * 16 + q * 4;         // aligned half-row base for this quad's k-slice
    F8 a1f, a2f;
#pragma unroll
    for (int i2 = 0; i2 < 4; ++i2) {
      a1f.u[i2] = Au[arow + hb + i2];
      a2f.u[i2] = A2u[arow + hb + i2];
    }
#pragma unroll
    for (int t2 = 0; t2 < 2; ++t2) {
      int n = t2 * 16 + ln;
      int baseT = n * 256 + (hb ^ ((n & 15) << 2));
      F8 bf;
#pragma unroll
      for (int i2 = 0; i2 < 4; ++i2) bf.u[i2] = xlsT[baseT + i2];
      acc1[t2] = __builtin_amdgcn_mfma_f32_16x16x32_bf16(a1f.s, bf.s, acc1[t2], 0, 0, 0);
      acc2[t2] = __builtin_amdgcn_mfma_f32_16x16x32_bf16(a2f.s, bf.s, acc2[t2], 0, 0, 0);
    }
  }
  int outb = bt * 16000;
#pragma unroll
  for (int t2 = 0; t2 < 2; ++t2) {
#pragma unroll
    for (int i2 = 0; i2 < 4; ++i2) {
      int r = rbase + q * 4 + i2;
      if (r < 500) {
        z1x[outb + r * 32 + t2 * 16 + ln] = acc1[t2][i2];
        z2x[outb + r * 32 + t2 * 16 + ln] = acc2[t2][i2];
      }
    }
  }
}

// ---------------- K3: MFMA fused attention: out = softmax(K K^T / sqrt(32)) @ V ----------------
__global__ __launch_bounds__(256, 2) void k_attn2(const float* __restrict__ keys,
                                                  const float* __restrict__ vals,
                                                  float* __restrict__ outp) {
  __shared__ u32 xls[8192];        // 512 rows x 16 u32 bf16-pairs, swizzled (32 KB)
  __shared__ u32 pch[4][272];      // per-wave P chunk: 16 x 17 u32 (4.25 KB)
  int tid = threadIdx.x, bt = blockIdx.x;
  const float* kb = keys + bt * 16000;
  for (int i = tid; i < 8192; i += 256) {
    int r = i >> 4, cu = i & 15;
    u32 u = 0;
    if (r < 500) {
      float2 g = *(const float2*)(kb + r * 32 + cu * 2);
      u = pk2(g.x, g.y);
    }
    xls[(r << 4) | (cu ^ (r & 15))] = u;
  }
  __syncthreads();
  int lane = tid & 63, wave = tid >> 6;
  int q = lane >> 4, ln = lane & 15;
  int rbase = blockIdx.y * 64 + wave * 16;
  union F8 { u32 u[4]; short8 s; };
  F8 af;
  {
    int r = rbase + ln;
#pragma unroll
    for (int i2 = 0; i2 < 4; ++i2)
      af.u[i2] = xls[(r << 4) | ((q * 4 + i2) ^ (r & 15))];
  }
  floatx4 acc[32];
#pragma unroll
  for (int ct = 0; ct < 32; ++ct) {
    int r2 = ct * 16 + ln;
    F8 bf;
#pragma unroll
    for (int i2 = 0; i2 < 4; ++i2)
      bf.u[i2] = xls[(r2 << 4) | ((q * 4 + i2) ^ (r2 & 15))];
    acc[ct] = __builtin_amdgcn_mfma_f32_16x16x32_bf16(af.s, bf.s,
              (floatx4){0.f, 0.f, 0.f, 0.f}, 0, 0, 0);
  }
  if (ln >= 4) {
#pragma unroll
    for (int i2 = 0; i2 < 4; ++i2) acc[31][i2] = -1e30f;
  }
  const float sc = 0.17677669529663687f;
  float inv[4];
#pragma unroll
  for (int i2 = 0; i2 < 4; ++i2) {
    float m = -1e30f;
#pragma unroll
    for (int ct = 0; ct < 32; ++ct) m = fmaxf(m, acc[ct][i2]);
#pragma unroll
    for (int d = 1; d < 16; d <<= 1) m = fmaxf(m, __shfl_xor(m, d));
    float s = 0.f;
#pragma unroll
    for (int ct = 0; ct < 32; ++ct) {
      float e = expf((acc[ct][i2] - m) * sc);
      acc[ct][i2] = e; s += e;
    }
#pragma unroll
    for (int d = 1; d < 16; d <<= 1) s += __shfl_xor(s, d);
    inv[i2] = 1.f / s;
  }
  const float* vb = vals + bt * 16000;
  floatx4 zacc[2] = {{0.f,0.f,0.f,0.f},{0.f,0.f,0.f,0.f}};
  u32* myp = pch[wave];
  u16* pw = (u16*)myp;
  for (int c2 = 0; c2 < 16; ++c2) {
#pragma unroll
    for (int t2 = 0; t2 < 2; ++t2) {
      int ct = c2 * 2 + t2;
#pragma unroll
      for (int i2 = 0; i2 < 4; ++i2)
        pw[(q * 4 + i2) * 34 + t2 * 16 + ln] = f2b(acc[ct][i2] * inv[i2]);
    }
    __syncthreads();
    F8 pa;
#pragma unroll
    for (int i2 = 0; i2 < 4; ++i2) pa.u[i2] = myp[ln * 17 + q * 4 + i2];
    int k0 = c2 * 32 + q * 8;
#pragma unroll
    for (int t2 = 0; t2 < 2; ++t2) {
      int n = t2 * 16 + ln;
      short8 bs;
#pragma unroll
      for (int j = 0; j < 8; ++j) {
        float v = vb[(k0 + j) * 32 + n];
        bs[j] = (short)(__float_as_uint(v) >> 16);
      }
      zacc[t2] = __builtin_amdgcn_mfma_f32_16x16x32_bf16(pa.s, bs, zacc[t2], 0, 0, 0);
    }
    __syncthreads();
  }
  int outb = bt * 16000;
#pragma unroll
  for (int t2 = 0; t2 < 2; ++t2) {
#pragma unroll
    for (int i2 = 0; i2 < 4; ++i2) {
      int r = rbase + q * 4 + i2;
      if (r < 500) outp[outb + r * 32 + t2 * 16 + ln] = zacc[t2][i2];
    }
  }
}

// ---------------- K4: mlp + gate + ct1 -> g2 ----------------
__global__ __launch_bounds__(256) void k_mlp(
    const float* __restrict__ h3x, const float* __restrict__ z1x, const float* __restrict__ z2x,
    const float* __restrict__ z3x, const float* __restrict__ z4x,
    const float* __restrict__ mlpW, const float* __restrict__ mlpB,
    const float* __restrict__ ct1W, const float* __restrict__ ct1B,
    float* __restrict__ g2w)
{
  __shared__ float Wm[10240];
  __shared__ float cat[32][161];
  __shared__ float ct1l[60];
  __shared__ float ct1bl[6];
  __shared__ float mbl[64];
  int tid = threadIdx.x;
  int b = blockIdx.y, n0 = blockIdx.x * 32;
  int nn = 500 - n0; if (nn > 32) nn = 32;
  for (int i = tid; i < 10240; i += 256) Wm[i] = mlpW[i];
  if (tid < 60) ct1l[tid] = ct1W[tid];
  if (tid < 6)  ct1bl[tid] = ct1B[tid];
  if (tid < 64) mbl[tid] = mlpB[tid];
  __syncthreads();
  int nl = tid & 31, slot = tid >> 5;
  bool act = nl < nn;
  int n = n0 + nl;
  float g2r[4][6];
#pragma unroll
  for (int k = 0; k < 4; ++k)
#pragma unroll
    for (int s = 0; s < 6; ++s) g2r[k][s] = 0.f;
  for (int t = 0; t < 10; ++t) {
    int rowbase = (b * 10 + t) * 500 + n0;
#pragma unroll
    for (int seg = 0; seg < 5; ++seg) {
      const float* sp = seg == 0 ? h3x : seg == 1 ? z1x : seg == 2 ? z2x : seg == 3 ? z3x : z4x;
      for (int i = tid; i < 1024; i += 256) {
        int nb = i >> 5, cc = i & 31;
        cat[nb][seg * 32 + cc] = (nb < nn) ? sp[(rowbase + nb) * 32 + cc] : 0.f;
      }
    }
    __syncthreads();
    if (act) {
      float hc[8];
#pragma unroll
      for (int k = 0; k < 8; ++k) hc[k] = mbl[slot + 8 * k];
      for (int cch = 0; cch < 160; ++cch) {
        float xvv = cat[nl][cch];
#pragma unroll
        for (int k = 0; k < 8; ++k) hc[k] += Wm[(slot + 8 * k) * 160 + cch] * xvv;
      }
#pragma unroll
      for (int k = 0; k < 4; ++k) {
        float gk = tanhf(hc[k]) * (1.f / (1.f + expf(-hc[k + 4])));
#pragma unroll
        for (int s = 0; s < 6; ++s) g2r[k][s] += gk * ct1l[s * 10 + t];
      }
    }
    __syncthreads();
  }
  if (act) {
#pragma unroll
    for (int k = 0; k < 4; ++k) {
      int cc = slot + 8 * k;
      int base = ((b * 32 + cc) * 500 + n) * 6;
#pragma unroll
      for (int s = 0; s < 6; ++s) g2w[base + s] = g2r[k][s] + ct1bl[s];
    }
  }
}

// ---------------- K4b: f1 ----------------
__global__ __launch_bounds__(256) void k_f1n(const float* __restrict__ g2w,
                                             const float* __restrict__ tc1W,
                                             float* __restrict__ f1w) {
  int i = blockIdx.x * 256 + threadIdx.x;
  if (i >= 48000) return;
  int b = i / 3000, rem = i - b * 3000, s = rem / 500, n = rem - s * 500;
  float a = 0.f;
  for (int c = 0; c < 32; ++c) a += g2w[((b * 32 + c) * 500 + n) * 6 + s] * tc1W[c];
  f1w[(b * 6 + s) * 500 + n] = a;
}

// ---------------- K5a: f2 ----------------
__global__ __launch_bounds__(64) void k_f2(const float* __restrict__ g2w,
                                           const float* __restrict__ c2W, float* __restrict__ f2w) {
  int b = blockIdx.x >> 5, c = blockIdx.x & 31, lane = threadIdx.x;
  float acc[6];
#pragma unroll
  for (int t = 0; t < 6; ++t) acc[t] = 0.f;
  for (int n = lane; n < 500; n += 64) {
    float w = c2W[n];
    const float* gp = g2w + ((b * 32 + c) * 500 + n) * 6;
#pragma unroll
    for (int t = 0; t < 6; ++t) acc[t] += w * gp[t];
  }
#pragma unroll
  for (int t = 0; t < 6; ++t)
    for (int off = 32; off; off >>= 1) acc[t] += __shfl_xor(acc[t], off);
  if (lane == 0) {
#pragma unroll
    for (int t = 0; t < 6; ++t) f2w[(b * 32 + c) * 6 + t] = acc[t];
  }
}

// ---------------- K5b: per-b TATT ----------------
__global__ __launch_bounds__(256) void k_tatt(
    const float* __restrict__ f1w, const float* __restrict__ tatw,
    const float* __restrict__ f2w, const float* __restrict__ tatb, const float* __restrict__ tatv,
    float* __restrict__ lg2w)
{
  __shared__ float mid[192];
  __shared__ float lgt[36];
  int b = blockIdx.x, tid = threadIdx.x;
  if (tid < 192) {
    int t = tid >> 5, c = tid & 31;
    float a = 0.f;
    const float* f1p = f1w + (b * 6 + t) * 500;
    for (int n = 0; n < 500; ++n) a += f1p[n] * tatw[n * 32 + c];
    mid[t * 32 + c] = a;
  }
  __syncthreads();
  if (tid < 36) {
    int t = tid / 6, s = tid - t * 6;
    float a = tatb[t * 6 + s];
    for (int c = 0; c < 32; ++c) a += mid[t * 32 + c] * f2w[(b * 32 + c) * 6 + s];
    lgt[t * 6 + s] = 1.f / (1.f + expf(-a));
  }
  __syncthreads();
  if (tid < 36) {
    int p = tid / 6, s = tid - p * 6;
    float a = 0.f;
#pragma unroll
    for (int t2 = 0; t2 < 6; ++t2) a += tatv[p * 6 + t2] * lgt[t2 * 6 + s];
    lg2w[(b * 6 + p) * 6 + s] = a;
  }
}

// ---------------- K5c: BN1 + softmax -> Tc ----------------
__global__ __launch_bounds__(128) void k_coefs(const float* __restrict__ lg2w,
    const float* __restrict__ bn1g, const float* __restrict__ bn1b, float* __restrict__ tcw) {
  __shared__ float mu[6], iv[6], gg[6], bb[6];
  int tid = threadIdx.x;
  if (tid < 6) {
    float s = 0.f, sq = 0.f;
    for (int b = 0; b < 16; ++b)
      for (int q = 0; q < 6; ++q) {
        float v = lg2w[(b * 6 + q) * 6 + tid];
        s += v; sq += v * v;
      }
    float m = s / 96.f;
    mu[tid] = m;
    iv[tid] = rsqrtf(sq / 96.f - m * m + 1e-5f);
    gg[tid] = bn1g[tid]; bb[tid] = bn1b[tid];
  }
  __syncthreads();
  for (int idx = tid; idx < 96; idx += 128) {
    int b = idx / 6, q = idx - b * 6;
    float v[6], mx = -1e30f;
#pragma unroll
    for (int l = 0; l < 6; ++l) {
      v[l] = (lg2w[(b * 6 + q) * 6 + l] - mu[l]) * iv[l] * gg[l] + bb[l];
      mx = fmaxf(mx, v[l]);
    }
    float tot = 0.f;
#pragma unroll
    for (int l = 0; l < 6; ++l) { v[l] = expf(v[l] - mx); tot += v[l]; }
    float inv = 1.f / tot;
#pragma unroll
    for (int l = 0; l < 6; ++l) tcw[(b * 6 + l) * 6 + q] = v[l] * inv;
  }
}

// ---------------- K6a: xo = leaky(g2@Tc)+res6, per-c sum/sumsq ----------------
__global__ __launch_bounds__(256) void k_xo(const float* __restrict__ g2w,
    const float* __restrict__ res6, const float* __restrict__ tcw,
    float* __restrict__ xow, float* __restrict__ stats) {
  __shared__ float Tcl[36];
  __shared__ float redS[32][8], redQ[32][8];
  int b = blockIdx.x, chunk = blockIdx.y, tid = threadIdx.x;
  if (tid < 36) Tcl[tid] = tcw[b * 36 + tid];
  __syncthreads();
  int c = tid & 31, sub = tid >> 5;
  int n0 = chunk * 50;
  float s = 0.f, sq = 0.f;
  for (int idx = sub; idx < 300; idx += 8) {
    int nl = idx / 6, q = idx - nl * 6;
    int n = n0 + nl;
    int base = ((b * 32 + c) * 500 + n) * 6;
    const float* gp = g2w + base;
    float xv = 0.f;
#pragma unroll
    for (int l = 0; l < 6; ++l) xv += gp[l] * Tcl[l * 6 + q];
    xv = xv > 0.f ? xv : 0.01f * xv;
    xv += res6[base + q];
    xow[base + q] = xv;
    s += xv; sq += xv * xv;
  }
  redS[c][sub] = s; redQ[c][sub] = sq;
  __syncthreads();
  if (sub == 0) {
    float ts = 0.f, tq = 0.f;
#pragma unroll
    for (int k = 0; k < 8; ++k) { ts += redS[c][k]; tq += redQ[c][k]; }
    atomicAdd(&stats[c], ts);
    atomicAdd(&stats[32 + c], tq);
  }
}

// ---------------- K6b: BN2 normalize -> FP32 out ----------------
__global__ __launch_bounds__(256) void k_out(const float* __restrict__ xow,
    const float* __restrict__ stats, const float* __restrict__ g2c, const float* __restrict__ b2c,
    float* __restrict__ out) {
  int base = (blockIdx.x * 256 + threadIdx.x) * 4;
#pragma unroll
  for (int k = 0; k < 4; ++k) {
    int i = base + k;
    int c = (i / 3000) & 31;
    float m = stats[c] * (1.f / 48000.f);
    float var = stats[32 + c] * (1.f / 48000.f) - m * m;
    out[i] = (xow[i] - m) * rsqrtf(var + 1e-5f) * g2c[c] + b2c[c];
  }
}

extern "C" void kernel_launch(void* const* d_in, const int* in_sizes, int n_in,
                              void* d_out, int out_size, void* d_ws, size_t ws_size,
                              hipStream_t stream)
{
  (void)in_sizes; (void)out_size;

  float* ws = (float*)d_ws;
  float* Af   = ws;                 // 250,000
  float* Wf   = Af + 250000;        // 65,536 (65,322 used)
  float* A2   = Wf + 65536;         // 250,000
  float* h3x  = A2 + 250000;        // 2,560,000 (B,T,N,32)
  float* z1x  = h3x + 2560000;
  float* z2x  = z1x + 2560000;
  float* z3x  = z2x + 2560000;
  float* z4x  = z3x + 2560000;
  float* res6 = z4x + 2560000;      // 1,536,000
  float* g2w  = res6 + 1536000;     // 1,536,000
  float* f1w  = g2w + 1536000;      // 48,000
  float* f2w  = f1w + 48000;        // 3,072
  float* lg2w = f2w + 3072;         // 576
  float* tcw  = lg2w + 576;         // 576
  float* stats= tcw + 576;          // 64
  int*   dtf  = (int*)(stats + 64); // 1 int
  float* xf   = z4x;                // x fp32 overlay: dead after k_front2, before k_attn2#2
  float* xow  = z1x;                // reuse z1 region after k_mlp
  u16*   Abf  = (u16*)g2w;          // 512x512 bf16 A pack (g2w region dead until k_mlp)
  u16*   A2bf = (u16*)(g2w + 131072); // 512x512 bf16 A2 pack
  float* WTp  = g2w + 262144;       // 25,600 transposed-weight pack (dead before k_mlp)
  if (ws_size < (size_t)16489952 * sizeof(float)) return;  // workspace guard

  // converted-weight offsets inside Wf (cumulative over dict inputs 2..28)
  const float* c1B  = Wf + 1024;
  const float* te1B = Wf + 3104;
  const float* qB   = Wf + 15456;
  const float* kB   = Wf + 27808;
  const float* lvB  = Wf + 31968;
  const float* loB  = Wf + 36128;
  const float* te2B = Wf + 38240;
  const float* mlpW = Wf + 38272;
  const float* mlpB = Wf + 48512;
  const float* ct1W = Wf + 48576;
  const float* ct1B = Wf + 48636;
  const float* tc1W = Wf + 48642;
  const float* tc2W = Wf + 48674;
  const float* tatw = Wf + 49174;
  const float* tatb = Wf + 65174;
  const float* tatv = Wf + 65210;
  const float* bn1g = Wf + 65246;
  const float* bn1b = Wf + 65252;
  const float* bn2g = Wf + 65258;
  const float* bn2b = Wf + 65290;

  Ptrs ps;
  for (int i = 0; i < 29; ++i) ps.p[i] = (i < n_in) ? d_in[i] : d_in[0];

  hipMemsetAsync(stats, 0, 64 * sizeof(float), stream);
  k_resolve<<<dim3(1),     64, 0, stream>>>(ps.p[25], dtf);
  k_cvt  <<<dim3(1232),    256, 0, stream>>>(ps, dtf, Af, Wf);
  k_cvtx <<<dim3(10000),   256, 0, stream>>>(ps.p[0], dtf, xf);
  k_wprep<<<dim3(100),     256, 0, stream>>>(Wf, WTp);
  k_a2   <<<dim3(2, 63),   256, 0, stream>>>(Af, A2);
  k_pk   <<<dim3(1024),    256, 0, stream>>>(Af, A2, Abf, A2bf);
  k_front2<<<dim3(2000),   256, 0, stream>>>(xf, WTp, c1B, te1B, qB, kB, lvB, loB,
                                             te2B, h3x, res6);
  k_z12m <<<dim3(160, 8),  256, 0, stream>>>(h3x, Abf, A2bf, z1x, z2x);
  k_attn2<<<dim3(160, 8),  256, 0, stream>>>(h3x, h3x, z3x);
  k_attn2<<<dim3(160, 8),  256, 0, stream>>>(h3x, z3x, z4x);
  k_mlp  <<<dim3(16, 16),  256, 0, stream>>>(h3x, z1x, z2x, z3x, z4x, mlpW, mlpB,
                                             ct1W, ct1B, g2w);
  k_f1n  <<<dim3(188),     256, 0, stream>>>(g2w, tc1W, f1w);
  k_f2   <<<dim3(512),      64, 0, stream>>>(g2w, tc2W, f2w);
  k_tatt <<<dim3(16),      256, 0, stream>>>(f1w, tatw, f2w, tatb, tatv, lg2w);
  k_coefs<<<dim3(1),       128, 0, stream>>>(lg2w, bn1g, bn1b, tcw);
  k_xo   <<<dim3(16, 10),  256, 0, stream>>>(g2w, res6, tcw, xow, stats);
  k_out  <<<dim3(1500),    256, 0, stream>>>(xow, stats, bn2g, bn2b, (float*)d_out);
}

// Round 2
// 580.132 us; speedup vs baseline: 1.8863x; 1.1691x over previous
//
#include <hip/hip_runtime.h>

typedef unsigned short u16;
typedef unsigned int u32;

__device__ __forceinline__ float b2f(u16 v) { return __uint_as_float((u32)v << 16); }
__device__ __forceinline__ float lopart(u32 u) { return __uint_as_float(u << 16); }
__device__ __forceinline__ float hipart(u32 u) { return __uint_as_float(u & 0xffff0000u); }
__device__ __forceinline__ u16 f2b(float f) {
  u32 u = __float_as_uint(f);
  u32 r = u + 0x7fffu + ((u >> 16) & 1u);
  return (u16)(r >> 16);
}
__device__ __forceinline__ u32 pk2(float a, float b) {
  return (u32)f2b(a) | ((u32)f2b(b) << 16);
}
__device__ __forceinline__ u32 cvtpk(float lo, float hi) {
  u32 r;
  asm("v_cvt_pk_bf16_f32 %0, %1, %2" : "=v"(r) : "v"(lo), "v"(hi));
  return r;
}

struct Ptrs { const void* p[29]; };

typedef __attribute__((ext_vector_type(8))) short short8;
typedef __attribute__((ext_vector_type(4))) float floatx4;

// ---------------- K-2: dtype flag (bn1_g[0]: bf16 pair 0x3F803F80 vs fp32 0x3F800000) ----------------
__global__ void k_resolve(const void* __restrict__ g1, int* __restrict__ dtf) {
  if (threadIdx.x == 0) {
    u32 w = *(const u32*)g1;
    *dtf = ((w & 0xffffu) != 0) ? 1 : 0;
  }
}

// ---------------- K-1: convert A + all weights to fp32 (C-order identity; dict order) ----------------
__global__ __launch_bounds__(256) void k_cvt(Ptrs ps, const int* __restrict__ dtf,
                                             float* __restrict__ Af, float* __restrict__ Wf) {
  bool BF = *dtf != 0;
  int i = blockIdx.x * 256 + threadIdx.x;
  if (i < 250000) {
    const void* pA = ps.p[1];
    Af[i] = BF ? b2f(((const u16*)pA)[i]) : ((const float*)pA)[i];
    return;
  }
  int j = i - 250000;
  if (j >= 65322) return;
  const int SZ[27] = {1024,32,2048,64,12288,64,12288,64,4096,64,4096,64,2048,32,
                      10240,64,60,6,32,500,16000,36,36,6,6,32,32};
  int t = 0, off = 0;
#pragma unroll
  for (int k = 0; k < 27; ++k) {
    if (t == k && j >= off + SZ[k]) { off += SZ[k]; t = k + 1; }
  }
  const void* src = ps.p[2 + t];
  int l = j - off;
  Wf[j] = BF ? b2f(((const u16*)src)[l]) : ((const float*)src)[l];
}

// ---------------- K-0b: x -> fp32 (identity C-order) ----------------
__global__ __launch_bounds__(256) void k_cvtx(const void* __restrict__ x, const int* __restrict__ dtf,
                                              float* __restrict__ xf) {
  bool BF = *dtf != 0;
  int i = blockIdx.x * 256 + threadIdx.x;
  if (i < 2560000) xf[i] = BF ? b2f(((const u16*)x)[i]) : ((const float*)x)[i];
}

// ---------------- K0: A2 = A @ A  (fp32) ----------------
__global__ __launch_bounds__(256) void k_a2(const float* __restrict__ Af, float* __restrict__ A2) {
  __shared__ float Arow[8][500];
  int tid = threadIdx.x;
  int j = blockIdx.x * 256 + tid;
  int i0 = blockIdx.y * 8;
  for (int i = tid; i < 4000; i += 256) {
    int r = i / 500, kk = i - r * 500;
    int ii = i0 + r; if (ii > 499) ii = 499;
    Arow[r][kk] = Af[ii * 500 + kk];
  }
  __syncthreads();
  if (j >= 500) return;
  float acc[8];
#pragma unroll
  for (int ii = 0; ii < 8; ++ii) acc[ii] = 0.f;
  for (int k = 0; k < 500; ++k) {
    float akj = Af[k * 500 + j];
#pragma unroll
    for (int ii = 0; ii < 8; ++ii) acc[ii] += Arow[ii][k] * akj;
  }
#pragma unroll
  for (int ii = 0; ii < 8; ++ii)
    if (i0 + ii < 500) A2[(i0 + ii) * 500 + j] = acc[ii];
}

// ---------------- K0b: pack A, A2 to zero-padded 512x512 bf16 ----------------
__global__ __launch_bounds__(256) void k_pk(const float* __restrict__ Af, const float* __restrict__ A2,
                                            u16* __restrict__ Abf, u16* __restrict__ A2bf) {
  int i = blockIdx.x * 256 + threadIdx.x;
  if (i >= 262144) return;
  int r = i >> 9, v = i & 511;
  bool in = (r < 500) && (v < 500);
  Abf[i]  = f2b(in ? Af[r * 500 + v] : 0.f);
  A2bf[i] = f2b(in ? A2[r * 500 + v] : 0.f);
}

// ---------------- K0c: transpose frontend weights into [k][o] layouts (coalesced per-lane reads) ----
// WT float layout:
//   te1T [0,2048)     : [c*64+o]         = te1W[o*32+c]
//   c1T  [2048,3072)  : [i*32+c]         = c1W[c*32+i]
//   qkT  [3072,15360) : u32 [(i*3+tap)*64+o] = pack(qW[o,i,tap], kW[o,i,tap]) as bf16 pair
//   lvT  [15360,19456): [i*64+o]         = lvW[o*64+i]
//   loT  [19456,23552): [j*64+o]         = loW[o*64+j]
//   te2T [23552,25600): [j*32+c]         = te2W[c*64+j]
// WBu (separate buffer): mlpW bf16 B-frag pack [kt][ct][lane][j], 10240 u16
__global__ __launch_bounds__(256) void k_wprep(const float* __restrict__ Wf, float* __restrict__ WT,
                                               u16* __restrict__ WBu) {
  int i = blockIdx.x * 256 + threadIdx.x;
  if (i < 2048) {
    int c = i >> 6, o = i & 63;
    WT[i] = Wf[1056 + o * 32 + c];
  } else if (i < 3072) {
    int j = i - 2048; int ii = j >> 5, c = j & 31;
    WT[i] = Wf[c * 32 + ii];
  } else if (i < 15360) {
    int j = i - 3072;
    int o = j & 63, it = j >> 6; int ii = it / 3, tap = it - ii * 3;
    int si = o * 192 + ii * 3 + tap;
    ((u32*)WT)[i] = pk2(Wf[3168 + si], Wf[15520 + si]);
  } else if (i < 19456) {
    int j = i - 15360; int ii = j >> 6, o = j & 63;
    WT[i] = Wf[27872 + o * 64 + ii];
  } else if (i < 23552) {
    int j = i - 19456; int jj = j >> 6, o = j & 63;
    WT[i] = Wf[32032 + o * 64 + jj];
  } else if (i < 25600) {
    int j = i - 23552; int jj = j >> 5, c = j & 31;
    WT[i] = Wf[36192 + c * 64 + jj];
  } else if (i < 35840) {
    // mlpW B-frag pack: lane (q,ln) of frag (kt,ct) holds W[k=kt*32+q*8+j][o=ct*16+ln]
    int j2 = i - 25600;
    int j = j2 & 7, lanev = (j2 >> 3) & 63, ct = (j2 >> 9) & 3, kt = j2 >> 11;
    int qv = lanev >> 4, lnv = lanev & 15;
    int o = ct * 16 + lnv, k = kt * 32 + qv * 8 + j;
    WBu[j2] = f2b(Wf[38272 + o * 160 + k]);
  }
}

// ---------------- K1: frontend, one (b,n) pair per WAVE, zero block barriers ----------------
// lane = output channel (64). Per-wave LDS arena (2368 floats, 16B aligned rows of 12):
//   phase          writes              reads
//   x load         x   [0,384)
//   residual                           x
//   h1             h1  [384,1152)      x
//   qkv (regs)                         h1 (broadcast b128)
//   q/k spill      q[0,768) k[768,1536)
//   scores+smax    P   [1536,2336)     q,k
//   PV (regs)                          P (+ v in regs)
//   o spill        o   [0,768)
//   lino           lo  [768,1536)      o (broadcast)
//   te2 + store                        lo
// In-order per-wave LDS + wave_barrier (compile-time fence) replaces __syncthreads.
__global__ __launch_bounds__(256, 4) void k_front2(
    const float* __restrict__ xf, const float* __restrict__ WT,
    const float* __restrict__ c1B, const float* __restrict__ te1B,
    const float* __restrict__ qB, const float* __restrict__ kB,
    const float* __restrict__ lvB, const float* __restrict__ loB,
    const float* __restrict__ te2B,
    float* __restrict__ h3x, float* __restrict__ res6)
{
  __shared__ __align__(16) float arena[4][2368];
  int tid = threadIdx.x;
  int wave = tid >> 6, lane = tid & 63;
  float* Aw = arena[wave];
  int pair = blockIdx.x * 4 + wave;
  int b = pair / 500, n = pair - b * 500;

  const float* te1T = WT;
  const float* c1T  = WT + 2048;
  const u32*   qkT  = (const u32*)(WT + 3072);
  const float* lvT  = WT + 15360;
  const float* loT  = WT + 19456;
  const float* te2T = WT + 23552;

  // ---- x -> LDS rows [c*12 + t]
  {
    int c0 = lane >> 1, hf = (lane & 1) * 5;
    const float* xp = xf + ((b * 32 + c0) * 500 + n) * 10 + hf;
    float* dst = Aw + c0 * 12 + hf;
#pragma unroll
    for (int k2 = 0; k2 < 5; ++k2) dst[k2] = xp[k2];
  }
  __builtin_amdgcn_wave_barrier();

  int cl = lane & 31, th = lane >> 5;

  // ---- residual: lane=(c, th), 3 time outputs each
  {
    float r0 = c1B[cl], r1 = r0, r2 = r0;
#pragma unroll 4
    for (int i = 0; i < 32; ++i) {
      float w = c1T[i * 32 + cl];
      const float* xr = Aw + i * 12 + 4 + th * 3;
      r0 += w * xr[0]; r1 += w * xr[1]; r2 += w * xr[2];
    }
    float* rp = res6 + ((b * 32 + cl) * 500 + n) * 6 + th * 3;
    rp[0] = r0; rp[1] = r1; rp[2] = r2;
  }

  // ---- h1: lane = out channel o, 10 t's in regs
  {
    float bb = te1B[lane];
    float h1r[10];
#pragma unroll
    for (int t = 0; t < 10; ++t) h1r[t] = bb;
#pragma unroll 4
    for (int c = 0; c < 32; ++c) {
      float w = te1T[c * 64 + lane];
      const float* xr = Aw + c * 12;
      float4 xa = *(const float4*)xr;
      float4 xb = *(const float4*)(xr + 4);
      float2 xc = *(const float2*)(xr + 8);
      h1r[0] += w * xa.x; h1r[1] += w * xa.y; h1r[2] += w * xa.z; h1r[3] += w * xa.w;
      h1r[4] += w * xb.x; h1r[5] += w * xb.y; h1r[6] += w * xb.z; h1r[7] += w * xb.w;
      h1r[8] += w * xc.x; h1r[9] += w * xc.y;
    }
    float* hp = Aw + 384 + lane * 12;
    *(float4*)hp       = make_float4(h1r[0], h1r[1], h1r[2], h1r[3]);
    *(float4*)(hp + 4) = make_float4(h1r[4], h1r[5], h1r[6], h1r[7]);
    *(float2*)(hp + 8) = make_float2(h1r[8], h1r[9]);
  }
  __builtin_amdgcn_wave_barrier();

  // ---- q,k,v: lane = o; 66 FMA per i-iteration, broadcast h1 rows
  float qr[10], kr[10], vr[10];
  {
    float bq = qB[lane], bk = kB[lane], bv = lvB[lane];
#pragma unroll
    for (int t = 0; t < 10; ++t) { qr[t] = bq; kr[t] = bk; vr[t] = bv; }
    const u32* qp0 = qkT + lane;
    const float* lp0 = lvT + lane;
#pragma unroll 2
    for (int i = 0; i < 64; ++i) {
      const float* hp2 = Aw + 384 + i * 12;
      float4 ha = *(const float4*)hp2;
      float4 hb = *(const float4*)(hp2 + 4);
      float2 hc = *(const float2*)(hp2 + 8);
      u32 u0 = qp0[i * 192];
      u32 u1 = qp0[i * 192 + 64];
      u32 u2 = qp0[i * 192 + 128];
      float wv = lp0[i * 64];
      float q0 = lopart(u0), q1 = lopart(u1), q2 = lopart(u2);
      float k0 = hipart(u0), k1 = hipart(u1), k2 = hipart(u2);
      float hh[10] = {ha.x, ha.y, ha.z, ha.w, hb.x, hb.y, hb.z, hb.w, hc.x, hc.y};
#pragma unroll
      for (int t = 0; t < 10; ++t) { float c_ = hh[t]; qr[t] += q1 * c_; kr[t] += k1 * c_; vr[t] += wv * c_; }
#pragma unroll
      for (int t = 1; t < 10; ++t) { float c_ = hh[t - 1]; qr[t] += q0 * c_; kr[t] += k0 * c_; }
#pragma unroll
      for (int t = 0; t < 9; ++t) { float c_ = hh[t + 1]; qr[t] += q2 * c_; kr[t] += k2 * c_; }
    }
  }
  // spill q,k (v stays in regs for PV)
  {
    float* qp = Aw + lane * 12;
    *(float4*)qp       = make_float4(qr[0], qr[1], qr[2], qr[3]);
    *(float4*)(qp + 4) = make_float4(qr[4], qr[5], qr[6], qr[7]);
    *(float2*)(qp + 8) = make_float2(qr[8], qr[9]);
    float* kp = Aw + 768 + lane * 12;
    *(float4*)kp       = make_float4(kr[0], kr[1], kr[2], kr[3]);
    *(float4*)(kp + 4) = make_float4(kr[4], kr[5], kr[6], kr[7]);
    *(float2*)(kp + 8) = make_float2(kr[8], kr[9]);
  }
  __builtin_amdgcn_wave_barrier();

  // ---- scores + softmax: 80 (head,row) rows over 2 passes
  {
#pragma unroll
    for (int pass = 0; pass < 2; ++pass) {
      int row = pass * 64 + lane;
      if (row < 80) {
        int h8 = (row / 10) * 8, r = row - (row / 10) * 10;
        float sv[10];
#pragma unroll
        for (int s = 0; s < 10; ++s) sv[s] = 0.f;
#pragma unroll 2
        for (int d = 0; d < 8; ++d) {
          int jj = h8 + d;
          float qv = Aw[jj * 12 + r];
          const float* kp2 = Aw + 768 + jj * 12;
          float4 ka = *(const float4*)kp2;
          float4 kb = *(const float4*)(kp2 + 4);
          float2 kc = *(const float2*)(kp2 + 8);
          sv[0] += qv * ka.x; sv[1] += qv * ka.y; sv[2] += qv * ka.z; sv[3] += qv * ka.w;
          sv[4] += qv * kb.x; sv[5] += qv * kb.y; sv[6] += qv * kb.z; sv[7] += qv * kb.w;
          sv[8] += qv * kc.x; sv[9] += qv * kc.y;
        }
        const float sc_ = 0.35355339059327373f;
        float mx = sv[0];
#pragma unroll
        for (int s = 1; s < 10; ++s) mx = fmaxf(mx, sv[s]);
        float tot = 0.f, ev[10];
#pragma unroll
        for (int s = 0; s < 10; ++s) { ev[s] = expf((sv[s] - mx) * sc_); tot += ev[s]; }
        float inv = 1.f / tot;
        float* pp = Aw + 1536 + row * 10;
#pragma unroll
        for (int s = 0; s < 10; ++s) pp[s] = ev[s] * inv;
      }
    }
  }
  __builtin_amdgcn_wave_barrier();

  // ---- PV: lane = j (head h=j>>3), v in regs, P broadcast per 8-lane group
  float orr[10];
  {
    const float* pb = Aw + 1536 + (lane >> 3) * 100;
#pragma unroll
    for (int t = 0; t < 10; ++t) {
      const float* pr = pb + t * 10;
      float a = 0.f;
#pragma unroll
      for (int s = 0; s < 10; ++s) a += pr[s] * vr[s];
      orr[t] = a;
    }
    float* op = Aw + lane * 12;   // overwrites q (dead)
    *(float4*)op       = make_float4(orr[0], orr[1], orr[2], orr[3]);
    *(float4*)(op + 4) = make_float4(orr[4], orr[5], orr[6], orr[7]);
    *(float2*)(op + 8) = make_float2(orr[8], orr[9]);
  }
  __builtin_amdgcn_wave_barrier();

  // ---- lino: lane = o
  {
    float bo = loB[lane];
    float lor[10];
#pragma unroll
    for (int t = 0; t < 10; ++t) lor[t] = bo;
    const float* lp0 = loT + lane;
#pragma unroll 2
    for (int j = 0; j < 64; ++j) {
      float w = lp0[j * 64];
      const float* op2 = Aw + j * 12;
      float4 oa = *(const float4*)op2;
      float4 ob = *(const float4*)(op2 + 4);
      float2 oc = *(const float2*)(op2 + 8);
      lor[0] += w * oa.x; lor[1] += w * oa.y; lor[2] += w * oa.z; lor[3] += w * oa.w;
      lor[4] += w * ob.x; lor[5] += w * ob.y; lor[6] += w * ob.z; lor[7] += w * ob.w;
      lor[8] += w * oc.x; lor[9] += w * oc.y;
    }
    float* sp = Aw + 768 + lane * 12;   // overwrites k (dead)
    *(float4*)sp       = make_float4(lor[0], lor[1], lor[2], lor[3]);
    *(float4*)(sp + 4) = make_float4(lor[4], lor[5], lor[6], lor[7]);
    *(float2*)(sp + 8) = make_float2(lor[8], lor[9]);
  }
  __builtin_amdgcn_wave_barrier();

  // ---- te2 + h3x store: lane = (c, th), 5 t's each
  {
    float bt2 = te2B[cl];
    float a5[5];
#pragma unroll
    for (int k2 = 0; k2 < 5; ++k2) a5[k2] = bt2;
    const float* tp0 = te2T + cl;
    const float* base = Aw + 768 + th * 5;
#pragma unroll 2
    for (int j = 0; j < 64; ++j) {
      float w = tp0[j * 32];
      const float* lp = base + j * 12;
#pragma unroll
      for (int k2 = 0; k2 < 5; ++k2) a5[k2] += w * lp[k2];
    }
    int t0 = th * 5;
#pragma unroll
    for (int k2 = 0; k2 < 5; ++k2)
      h3x[((b * 10 + t0 + k2) * 500 + n) * 32 + cl] = a5[k2];
  }
}

// ---------------- K2: MFMA z1 = A @ XT, z2 = A2 @ XT ----------------
__global__ __launch_bounds__(256, 4) void k_z12m(const float* __restrict__ h3x,
    const u16* __restrict__ Abf, const u16* __restrict__ A2bf,
    float* __restrict__ z1x, float* __restrict__ z2x) {
  __shared__ u32 xlsT[8192];     // [n][half-row] pairs, swizzled (32 KB)
  int tid = threadIdx.x, bt = blockIdx.x;
  const float* src = h3x + bt * 16000;
  for (int i = tid; i < 8192; i += 256) {
    int n = i & 31, h = i >> 5;
    int r0 = 2 * h;
    float v0 = (r0 < 500) ? src[r0 * 32 + n] : 0.f;
    float v1 = (r0 + 1 < 500) ? src[(r0 + 1) * 32 + n] : 0.f;
    xlsT[n * 256 + (((h & 0xFC) ^ ((n & 15) << 2)) | (h & 3))] = pk2(v0, v1);
  }
  __syncthreads();
  int lane = tid & 63, wave = tid >> 6;
  int q = lane >> 4, ln = lane & 15;
  int rbase = blockIdx.y * 64 + wave * 16;
  const u32* Au = (const u32*)Abf;
  const u32* A2u = (const u32*)A2bf;
  int arow = (rbase + ln) * 256;
  union F8 { u32 u[4]; short8 s; };
  floatx4 acc1[2] = {{0.f,0.f,0.f,0.f},{0.f,0.f,0.f,0.f}};
  floatx4 acc2[2] = {{0.f,0.f,0.f,0.f},{0.f,0.f,0.f,0.f}};
  for (int c2 = 0; c2 < 16; ++c2) {
    int hb = c2 * 16 + q * 4;         // aligned half-row base for this quad's k-slice
    F8 a1f, a2f;
#pragma unroll
    for (int i2 = 0; i2 < 4; ++i2) {
      a1f.u[i2] = Au[arow + hb + i2];
      a2f.u[i2] = A2u[arow + hb + i2];
    }
#pragma unroll
    for (int t2 = 0; t2 < 2; ++t2) {
      int n = t2 * 16 + ln;
      int baseT = n * 256 + (hb ^ ((n & 15) << 2));
      F8 bf;
#pragma unroll
      for (int i2 = 0; i2 < 4; ++i2) bf.u[i2] = xlsT[baseT + i2];
      acc1[t2] = __builtin_amdgcn_mfma_f32_16x16x32_bf16(a1f.s, bf.s, acc1[t2], 0, 0, 0);
      acc2[t2] = __builtin_amdgcn_mfma_f32_16x16x32_bf16(a2f.s, bf.s, acc2[t2], 0, 0, 0);
    }
  }
  int outb = bt * 16000;
#pragma unroll
  for (int t2 = 0; t2 < 2; ++t2) {
#pragma unroll
    for (int i2 = 0; i2 < 4; ++i2) {
      int r = rbase + q * 4 + i2;
      if (r < 500) {
        z1x[outb + r * 32 + t2 * 16 + ln] = acc1[t2][i2];
        z2x[outb + r * 32 + t2 * 16 + ln] = acc2[t2][i2];
      }
    }
  }
}

// ---------------- K3: MFMA fused attention: out = softmax(K K^T / sqrt(32)) @ V ----------------
__global__ __launch_bounds__(256, 2) void k_attn2(const float* __restrict__ keys,
                                                  const float* __restrict__ vals,
                                                  float* __restrict__ outp) {
  __shared__ u32 xls[8192];        // 512 rows x 16 u32 bf16-pairs, swizzled (32 KB)
  __shared__ u32 pch[4][272];      // per-wave P chunk: 16 x 17 u32 (4.25 KB)
  int tid = threadIdx.x, bt = blockIdx.x;
  const float* kb = keys + bt * 16000;
  for (int i = tid; i < 8192; i += 256) {
    int r = i >> 4, cu = i & 15;
    u32 u = 0;
    if (r < 500) {
      float2 g = *(const float2*)(kb + r * 32 + cu * 2);
      u = pk2(g.x, g.y);
    }
    xls[(r << 4) | (cu ^ (r & 15))] = u;
  }
  __syncthreads();
  int lane = tid & 63, wave = tid >> 6;
  int q = lane >> 4, ln = lane & 15;
  int rbase = blockIdx.y * 64 + wave * 16;
  union F8 { u32 u[4]; short8 s; };
  F8 af;
  {
    int r = rbase + ln;
#pragma unroll
    for (int i2 = 0; i2 < 4; ++i2)
      af.u[i2] = xls[(r << 4) | ((q * 4 + i2) ^ (r & 15))];
  }
  floatx4 acc[32];
#pragma unroll
  for (int ct = 0; ct < 32; ++ct) {
    int r2 = ct * 16 + ln;
    F8 bf;
#pragma unroll
    for (int i2 = 0; i2 < 4; ++i2)
      bf.u[i2] = xls[(r2 << 4) | ((q * 4 + i2) ^ (r2 & 15))];
    acc[ct] = __builtin_amdgcn_mfma_f32_16x16x32_bf16(af.s, bf.s,
              (floatx4){0.f, 0.f, 0.f, 0.f}, 0, 0, 0);
  }
  if (ln >= 4) {
#pragma unroll
    for (int i2 = 0; i2 < 4; ++i2) acc[31][i2] = -1e30f;
  }
  const float sc = 0.17677669529663687f;
  float inv[4];
#pragma unroll
  for (int i2 = 0; i2 < 4; ++i2) {
    float m = -1e30f;
#pragma unroll
    for (int ct = 0; ct < 32; ++ct) m = fmaxf(m, acc[ct][i2]);
#pragma unroll
    for (int d = 1; d < 16; d <<= 1) m = fmaxf(m, __shfl_xor(m, d));
    float s = 0.f;
#pragma unroll
    for (int ct = 0; ct < 32; ++ct) {
      float e = expf((acc[ct][i2] - m) * sc);
      acc[ct][i2] = e; s += e;
    }
#pragma unroll
    for (int d = 1; d < 16; d <<= 1) s += __shfl_xor(s, d);
    inv[i2] = 1.f / s;
  }
  const float* vb = vals + bt * 16000;
  floatx4 zacc[2] = {{0.f,0.f,0.f,0.f},{0.f,0.f,0.f,0.f}};
  u32* myp = pch[wave];
  u16* pw = (u16*)myp;
  for (int c2 = 0; c2 < 16; ++c2) {
#pragma unroll
    for (int t2 = 0; t2 < 2; ++t2) {
      int ct = c2 * 2 + t2;
#pragma unroll
      for (int i2 = 0; i2 < 4; ++i2)
        pw[(q * 4 + i2) * 34 + t2 * 16 + ln] = f2b(acc[ct][i2] * inv[i2]);
    }
    __syncthreads();
    F8 pa;
#pragma unroll
    for (int i2 = 0; i2 < 4; ++i2) pa.u[i2] = myp[ln * 17 + q * 4 + i2];
    int k0 = c2 * 32 + q * 8;
#pragma unroll
    for (int t2 = 0; t2 < 2; ++t2) {
      int n = t2 * 16 + ln;
      short8 bs;
#pragma unroll
      for (int j = 0; j < 8; ++j) {
        float v = vb[(k0 + j) * 32 + n];
        bs[j] = (short)(__float_as_uint(v) >> 16);
      }
      zacc[t2] = __builtin_amdgcn_mfma_f32_16x16x32_bf16(pa.s, bs, zacc[t2], 0, 0, 0);
    }
    __syncthreads();
  }
  int outb = bt * 16000;
#pragma unroll
  for (int t2 = 0; t2 < 2; ++t2) {
#pragma unroll
    for (int i2 = 0; i2 < 4; ++i2) {
      int r = rbase + q * 4 + i2;
      if (r < 500) outp[outb + r * 32 + t2 * 16 + ln] = zacc[t2][i2];
    }
  }
}

// ---------------- K4: MFMA mlp + gate + fused ct1 -> g2 ----------------
// Wave = (b, 8 n's). A-tile rows pack 2 t's x 8 n's: row = t_local*8 + nl.
// 5 tiles cover t=0..9; 5 K-steps (K=160) read segments straight from h3x/z1..z4
// (rows are contiguous 32-float runs -> 2x float4 + v_cvt_pk_bf16_f32).
// Gate: channel c pairs col-tiles 0<->2, 1<->3 in-lane; ct1 contraction over t
// accumulates in regs; lane pair q <-> q^2 holds even/odd t -> one shfl_xor(32).
__global__ __launch_bounds__(256, 2) void k_gate(
    const float* __restrict__ h3x, const float* __restrict__ z1x, const float* __restrict__ z2x,
    const float* __restrict__ z3x, const float* __restrict__ z4x,
    const u32* __restrict__ WBq, const float* __restrict__ mlpB,
    const float* __restrict__ ct1W, const float* __restrict__ ct1B,
    float* __restrict__ g2w)
{
  __shared__ u32 wlds[5120];       // 20 KB: 20 B-frags x 64 lanes x 4 u32
  int tid = threadIdx.x;
  for (int i = tid; i < 5120; i += 256) wlds[i] = WBq[i];
  __syncthreads();
  int lane = tid & 63, wave = tid >> 6;
  int q = lane >> 4, ln = lane & 15;
  int b = blockIdx.y;
  int n0 = blockIdx.x * 32 + wave * 8;
  int nA = n0 + (ln & 7);          // A-row n for this lane
  int tAb = ln >> 3;               // A-row t_local (0/1)
  int nD = n0 + (q & 1) * 4;       // D-row n base (n = nD + i)
  int tDb = q >> 1;                // D-row t_local
  float g2a[4][2][6];
#pragma unroll
  for (int i = 0; i < 4; ++i)
#pragma unroll
    for (int ch = 0; ch < 2; ++ch)
#pragma unroll
      for (int s = 0; s < 6; ++s) g2a[i][ch][s] = 0.f;
  float bias[4];
#pragma unroll
  for (int ct = 0; ct < 4; ++ct) bias[ct] = mlpB[ct * 16 + ln];
  union F8 { u32 u[4]; short8 s; };
  for (int tile = 0; tile < 5; ++tile) {
    int tA = tile * 2 + tAb;
    int offA = (((b * 10 + tA) * 500) + nA) * 32 + q * 8;
    floatx4 acc[4];
#pragma unroll
    for (int ct = 0; ct < 4; ++ct) acc[ct] = (floatx4){bias[ct], bias[ct], bias[ct], bias[ct]};
#pragma unroll
    for (int kt = 0; kt < 5; ++kt) {
      const float* sp = kt == 0 ? h3x : kt == 1 ? z1x : kt == 2 ? z2x : kt == 3 ? z3x : z4x;
      float4 a0 = *(const float4*)(sp + offA);
      float4 a1 = *(const float4*)(sp + offA + 4);
      F8 af;
      af.u[0] = cvtpk(a0.x, a0.y);
      af.u[1] = cvtpk(a0.z, a0.w);
      af.u[2] = cvtpk(a1.x, a1.y);
      af.u[3] = cvtpk(a1.z, a1.w);
#pragma unroll
      for (int ct = 0; ct < 4; ++ct) {
        F8 bfr;
        const u32* wp = wlds + (((kt * 4 + ct) << 6) + lane) * 4;
#pragma unroll
        for (int i2 = 0; i2 < 4; ++i2) bfr.u[i2] = wp[i2];
        acc[ct] = __builtin_amdgcn_mfma_f32_16x16x32_bf16(af.s, bfr.s, acc[ct], 0, 0, 0);
      }
    }
    int tD = tile * 2 + tDb;
    float c6[6];
#pragma unroll
    for (int s = 0; s < 6; ++s) c6[s] = ct1W[s * 10 + tD];
#pragma unroll
    for (int i = 0; i < 4; ++i) {
      float e0 = __expf(2.f * acc[0][i]);
      float g0 = ((e0 - 1.f) / (e0 + 1.f)) * (1.f / (1.f + __expf(-acc[2][i])));
      float e1 = __expf(2.f * acc[1][i]);
      float g1 = ((e1 - 1.f) / (e1 + 1.f)) * (1.f / (1.f + __expf(-acc[3][i])));
#pragma unroll
      for (int s = 0; s < 6; ++s) {
        g2a[i][0][s] += g0 * c6[s];
        g2a[i][1][s] += g1 * c6[s];
      }
    }
  }
  // combine even-t (q=0,1) and odd-t (q=2,3) partial sums: lane pair = lane ^ 32
#pragma unroll
  for (int i = 0; i < 4; ++i)
#pragma unroll
    for (int ch = 0; ch < 2; ++ch)
#pragma unroll
      for (int s = 0; s < 6; ++s)
        g2a[i][ch][s] += __shfl_xor(g2a[i][ch][s], 32);
  if (q < 2) {
#pragma unroll
    for (int i = 0; i < 4; ++i) {
      int n = nD + i;
      if (n < 500) {
#pragma unroll
        for (int ch = 0; ch < 2; ++ch) {
          int c = ln + ch * 16;
          float* gp = g2w + ((b * 32 + c) * 500 + n) * 6;
#pragma unroll
          for (int s = 0; s < 6; ++s) gp[s] = g2a[i][ch][s] + ct1B[s];
        }
      }
    }
  }
}

// ---------------- K4b: f1 ----------------
__global__ __launch_bounds__(256) void k_f1n(const float* __restrict__ g2w,
                                             const float* __restrict__ tc1W,
                                             float* __restrict__ f1w) {
  int i = blockIdx.x * 256 + threadIdx.x;
  if (i >= 48000) return;
  int b = i / 3000, rem = i - b * 3000, s = rem / 500, n = rem - s * 500;
  float a = 0.f;
  for (int c = 0; c < 32; ++c) a += g2w[((b * 32 + c) * 500 + n) * 6 + s] * tc1W[c];
  f1w[(b * 6 + s) * 500 + n] = a;
}

// ---------------- K5a: f2 ----------------
__global__ __launch_bounds__(64) void k_f2(const float* __restrict__ g2w,
                                           const float* __restrict__ c2W, float* __restrict__ f2w) {
  int b = blockIdx.x >> 5, c = blockIdx.x & 31, lane = threadIdx.x;
  float acc[6];
#pragma unroll
  for (int t = 0; t < 6; ++t) acc[t] = 0.f;
  for (int n = lane; n < 500; n += 64) {
    float w = c2W[n];
    const float* gp = g2w + ((b * 32 + c) * 500 + n) * 6;
#pragma unroll
    for (int t = 0; t < 6; ++t) acc[t] += w * gp[t];
  }
#pragma unroll
  for (int t = 0; t < 6; ++t)
    for (int off = 32; off; off >>= 1) acc[t] += __shfl_xor(acc[t], off);
  if (lane == 0) {
#pragma unroll
    for (int t = 0; t < 6; ++t) f2w[(b * 32 + c) * 6 + t] = acc[t];
  }
}

// ---------------- K5b: per-b TATT ----------------
__global__ __launch_bounds__(256) void k_tatt(
    const float* __restrict__ f1w, const float* __restrict__ tatw,
    const float* __restrict__ f2w, const float* __restrict__ tatb, const float* __restrict__ tatv,
    float* __restrict__ lg2w)
{
  __shared__ float mid[192];
  __shared__ float lgt[36];
  int b = blockIdx.x, tid = threadIdx.x;
  if (tid < 192) {
    int t = tid >> 5, c = tid & 31;
    float a = 0.f;
    const float* f1p = f1w + (b * 6 + t) * 500;
    for (int n = 0; n < 500; ++n) a += f1p[n] * tatw[n * 32 + c];
    mid[t * 32 + c] = a;
  }
  __syncthreads();
  if (tid < 36) {
    int t = tid / 6, s = tid - t * 6;
    float a = tatb[t * 6 + s];
    for (int c = 0; c < 32; ++c) a += mid[t * 32 + c] * f2w[(b * 32 + c) * 6 + s];
    lgt[t * 6 + s] = 1.f / (1.f + expf(-a));
  }
  __syncthreads();
  if (tid < 36) {
    int p = tid / 6, s = tid - p * 6;
    float a = 0.f;
#pragma unroll
    for (int t2 = 0; t2 < 6; ++t2) a += tatv[p * 6 + t2] * lgt[t2 * 6 + s];
    lg2w[(b * 6 + p) * 6 + s] = a;
  }
}

// ---------------- K5c: BN1 + softmax -> Tc ----------------
__global__ __launch_bounds__(128) void k_coefs(const float* __restrict__ lg2w,
    const float* __restrict__ bn1g, const float* __restrict__ bn1b, float* __restrict__ tcw) {
  __shared__ float mu[6], iv[6], gg[6], bb[6];
  int tid = threadIdx.x;
  if (tid < 6) {
    float s = 0.f, sq = 0.f;
    for (int b = 0; b < 16; ++b)
      for (int q = 0; q < 6; ++q) {
        float v = lg2w[(b * 6 + q) * 6 + tid];
        s += v; sq += v * v;
      }
    float m = s / 96.f;
    mu[tid] = m;
    iv[tid] = rsqrtf(sq / 96.f - m * m + 1e-5f);
    gg[tid] = bn1g[tid]; bb[tid] = bn1b[tid];
  }
  __syncthreads();
  for (int idx = tid; idx < 96; idx += 128) {
    int b = idx / 6, q = idx - b * 6;
    float v[6], mx = -1e30f;
#pragma unroll
    for (int l = 0; l < 6; ++l) {
      v[l] = (lg2w[(b * 6 + q) * 6 + l] - mu[l]) * iv[l] * gg[l] + bb[l];
      mx = fmaxf(mx, v[l]);
    }
    float tot = 0.f;
#pragma unroll
    for (int l = 0; l < 6; ++l) { v[l] = expf(v[l] - mx); tot += v[l]; }
    float inv = 1.f / tot;
#pragma unroll
    for (int l = 0; l < 6; ++l) tcw[(b * 6 + l) * 6 + q] = v[l] * inv;
  }
}

// ---------------- K6a: xo = leaky(g2@Tc)+res6, per-c sum/sumsq ----------------
__global__ __launch_bounds__(256) void k_xo(const float* __restrict__ g2w,
    const float* __restrict__ res6, const float* __restrict__ tcw,
    float* __restrict__ xow, float* __restrict__ stats) {
  __shared__ float Tcl[36];
  __shared__ float redS[32][8], redQ[32][8];
  int b = blockIdx.x, chunk = blockIdx.y, tid = threadIdx.x;
  if (tid < 36) Tcl[tid] = tcw[b * 36 + tid];
  __syncthreads();
  int c = tid & 31, sub = tid >> 5;
  int n0 = chunk * 50;
  float s = 0.f, sq = 0.f;
  for (int idx = sub; idx < 300; idx += 8) {
    int nl = idx / 6, q = idx - nl * 6;
    int n = n0 + nl;
    int base = ((b * 32 + c) * 500 + n) * 6;
    const float* gp = g2w + base;
    float xv = 0.f;
#pragma unroll
    for (int l = 0; l < 6; ++l) xv += gp[l] * Tcl[l * 6 + q];
    xv = xv > 0.f ? xv : 0.01f * xv;
    xv += res6[base + q];
    xow[base + q] = xv;
    s += xv; sq += xv * xv;
  }
  redS[c][sub] = s; redQ[c][sub] = sq;
  __syncthreads();
  if (sub == 0) {
    float ts = 0.f, tq = 0.f;
#pragma unroll
    for (int k = 0; k < 8; ++k) { ts += redS[c][k]; tq += redQ[c][k]; }
    atomicAdd(&stats[c], ts);
    atomicAdd(&stats[32 + c], tq);
  }
}

// ---------------- K6b: BN2 normalize -> FP32 out ----------------
__global__ __launch_bounds__(256) void k_out(const float* __restrict__ xow,
    const float* __restrict__ stats, const float* __restrict__ g2c, const float* __restrict__ b2c,
    float* __restrict__ out) {
  int base = (blockIdx.x * 256 + threadIdx.x) * 4;
#pragma unroll
  for (int k = 0; k < 4; ++k) {
    int i = base + k;
    int c = (i / 3000) & 31;
    float m = stats[c] * (1.f / 48000.f);
    float var = stats[32 + c] * (1.f / 48000.f) - m * m;
    out[i] = (xow[i] - m) * rsqrtf(var + 1e-5f) * g2c[c] + b2c[c];
  }
}

extern "C" void kernel_launch(void* const* d_in, const int* in_sizes, int n_in,
                              void* d_out, int out_size, void* d_ws, size_t ws_size,
                              hipStream_t stream)
{
  (void)in_sizes; (void)out_size;

  float* ws = (float*)d_ws;
  float* Af   = ws;                 // 250,000
  float* Wf   = Af + 250000;        // 65,536 (65,322 used)
  float* A2   = Wf + 65536;         // 250,000
  float* h3x  = A2 + 250000;        // 2,560,000 (B,T,N,32)
  float* z1x  = h3x + 2560000;
  float* z2x  = z1x + 2560000;
  float* z3x  = z2x + 2560000;
  float* z4x  = z3x + 2560000;
  float* res6 = z4x + 2560000;      // 1,536,000
  float* g2w  = res6 + 1536000;     // 1,536,000
  float* f1w  = g2w + 1536000;      // 48,000
  float* f2w  = f1w + 48000;        // 3,072
  float* lg2w = f2w + 3072;         // 576
  float* tcw  = lg2w + 576;         // 576
  float* stats= tcw + 576;          // 64
  int*   dtf  = (int*)(stats + 64); // 1 int
  float* xf   = z4x;                // x fp32 overlay: dead after k_front2, before k_attn2#2
  float* xow  = z1x;                // reuse z1 region after k_gate
  u16*   Abf  = (u16*)g2w;          // 512x512 bf16 A pack (g2w region dead until k_gate)
  u16*   A2bf = (u16*)(g2w + 131072); // 512x512 bf16 A2 pack
  float* WTp  = g2w + 262144;       // 25,600 transposed-weight pack (dead before k_gate)
  u16*   WBu  = (u16*)f1w;          // 10,240 u16 mlpW B-frag pack (f1w region dead until k_f1n)
  if (ws_size < (size_t)16489952 * sizeof(float)) return;  // workspace guard

  // converted-weight offsets inside Wf (cumulative over dict inputs 2..28)
  const float* c1B  = Wf + 1024;
  const float* te1B = Wf + 3104;
  const float* qB   = Wf + 15456;
  const float* kB   = Wf + 27808;
  const float* lvB  = Wf + 31968;
  const float* loB  = Wf + 36128;
  const float* te2B = Wf + 38240;
  const float* mlpB = Wf + 48512;
  const float* ct1W = Wf + 48576;
  const float* ct1B = Wf + 48636;
  const float* tc1W = Wf + 48642;
  const float* tc2W = Wf + 48674;
  const float* tatw = Wf + 49174;
  const float* tatb = Wf + 65174;
  const float* tatv = Wf + 65210;
  const float* bn1g = Wf + 65246;
  const float* bn1b = Wf + 65252;
  const float* bn2g = Wf + 65258;
  const float* bn2b = Wf + 65290;

  Ptrs ps;
  for (int i = 0; i < 29; ++i) ps.p[i] = (i < n_in) ? d_in[i] : d_in[0];

  hipMemsetAsync(stats, 0, 64 * sizeof(float), stream);
  k_resolve<<<dim3(1),     64, 0, stream>>>(ps.p[25], dtf);
  k_cvt  <<<dim3(1232),    256, 0, stream>>>(ps, dtf, Af, Wf);
  k_cvtx <<<dim3(10000),   256, 0, stream>>>(ps.p[0], dtf, xf);
  k_wprep<<<dim3(140),     256, 0, stream>>>(Wf, WTp, WBu);
  k_a2   <<<dim3(2, 63),   256, 0, stream>>>(Af, A2);
  k_pk   <<<dim3(1024),    256, 0, stream>>>(Af, A2, Abf, A2bf);
  k_front2<<<dim3(2000),   256, 0, stream>>>(xf, WTp, c1B, te1B, qB, kB, lvB, loB,
                                             te2B, h3x, res6);
  k_z12m <<<dim3(160, 8),  256, 0, stream>>>(h3x, Abf, A2bf, z1x, z2x);
  k_attn2<<<dim3(160, 8),  256, 0, stream>>>(h3x, h3x, z3x);
  k_attn2<<<dim3(160, 8),  256, 0, stream>>>(h3x, z3x, z4x);
  k_gate <<<dim3(16, 16),  256, 0, stream>>>(h3x, z1x, z2x, z3x, z4x,
                                             (const u32*)WBu, mlpB, ct1W, ct1B, g2w);
  k_f1n  <<<dim3(188),     256, 0, stream>>>(g2w, tc1W, f1w);
  k_f2   <<<dim3(512),      64, 0, stream>>>(g2w, tc2W, f2w);
  k_tatt <<<dim3(16),      256, 0, stream>>>(f1w, tatw, f2w, tatb, tatv, lg2w);
  k_coefs<<<dim3(1),       128, 0, stream>>>(lg2w, bn1g, bn1b, tcw);
  k_xo   <<<dim3(16, 10),  256, 0, stream>>>(g2w, res6, tcw, xow, stats);
  k_out  <<<dim3(1500),    256, 0, stream>>>(xow, stats, bn2g, bn2b, (float*)d_out);
}

// Round 3
// 553.819 us; speedup vs baseline: 1.9759x; 1.0475x over previous
//
#include <hip/hip_runtime.h>

typedef unsigned short u16;
typedef unsigned int u32;

__device__ __forceinline__ float b2f(u16 v) { return __uint_as_float((u32)v << 16); }
__device__ __forceinline__ float lopart(u32 u) { return __uint_as_float(u << 16); }
__device__ __forceinline__ float hipart(u32 u) { return __uint_as_float(u & 0xffff0000u); }
__device__ __forceinline__ u16 f2b(float f) {
  u32 u = __float_as_uint(f);
  u32 r = u + 0x7fffu + ((u >> 16) & 1u);
  return (u16)(r >> 16);
}
__device__ __forceinline__ u32 pk2(float a, float b) {
  return (u32)f2b(a) | ((u32)f2b(b) << 16);
}
__device__ __forceinline__ u32 cvtpk(float lo, float hi) {
  u32 r;
  asm("v_cvt_pk_bf16_f32 %0, %1, %2" : "=v"(r) : "v"(lo), "v"(hi));
  return r;
}

struct Ptrs { const void* p[29]; };

typedef __attribute__((ext_vector_type(8))) short short8;
typedef __attribute__((ext_vector_type(4))) float floatx4;

// ---------------- K-2: dtype flag (bn1_g[0]: bf16 pair 0x3F803F80 vs fp32 0x3F800000) ----------------
__global__ void k_resolve(const void* __restrict__ g1, int* __restrict__ dtf) {
  if (threadIdx.x == 0) {
    u32 w = *(const u32*)g1;
    *dtf = ((w & 0xffffu) != 0) ? 1 : 0;
  }
}

// ---------------- K-1: convert A + all weights to fp32 (C-order identity; dict order) ----------------
__global__ __launch_bounds__(256) void k_cvt(Ptrs ps, const int* __restrict__ dtf,
                                             float* __restrict__ Af, float* __restrict__ Wf) {
  bool BF = *dtf != 0;
  int i = blockIdx.x * 256 + threadIdx.x;
  if (i < 250000) {
    const void* pA = ps.p[1];
    Af[i] = BF ? b2f(((const u16*)pA)[i]) : ((const float*)pA)[i];
    return;
  }
  int j = i - 250000;
  if (j >= 65322) return;
  const int SZ[27] = {1024,32,2048,64,12288,64,12288,64,4096,64,4096,64,2048,32,
                      10240,64,60,6,32,500,16000,36,36,6,6,32,32};
  int t = 0, off = 0;
#pragma unroll
  for (int k = 0; k < 27; ++k) {
    if (t == k && j >= off + SZ[k]) { off += SZ[k]; t = k + 1; }
  }
  const void* src = ps.p[2 + t];
  int l = j - off;
  Wf[j] = BF ? b2f(((const u16*)src)[l]) : ((const float*)src)[l];
}

// ---------------- K-0b: x -> fp32 (identity C-order) ----------------
__global__ __launch_bounds__(256) void k_cvtx(const void* __restrict__ x, const int* __restrict__ dtf,
                                              float* __restrict__ xf) {
  bool BF = *dtf != 0;
  int i = blockIdx.x * 256 + threadIdx.x;
  if (i < 2560000) xf[i] = BF ? b2f(((const u16*)x)[i]) : ((const float*)x)[i];
}

// ---------------- K0: A2 = A @ A  (fp32) ----------------
__global__ __launch_bounds__(256) void k_a2(const float* __restrict__ Af, float* __restrict__ A2) {
  __shared__ float Arow[8][500];
  int tid = threadIdx.x;
  int j = blockIdx.x * 256 + tid;
  int i0 = blockIdx.y * 8;
  for (int i = tid; i < 4000; i += 256) {
    int r = i / 500, kk = i - r * 500;
    int ii = i0 + r; if (ii > 499) ii = 499;
    Arow[r][kk] = Af[ii * 500 + kk];
  }
  __syncthreads();
  if (j >= 500) return;
  float acc[8];
#pragma unroll
  for (int ii = 0; ii < 8; ++ii) acc[ii] = 0.f;
  for (int k = 0; k < 500; ++k) {
    float akj = Af[k * 500 + j];
#pragma unroll
    for (int ii = 0; ii < 8; ++ii) acc[ii] += Arow[ii][k] * akj;
  }
#pragma unroll
  for (int ii = 0; ii < 8; ++ii)
    if (i0 + ii < 500) A2[(i0 + ii) * 500 + j] = acc[ii];
}

// ---------------- K0b: pack A, A2 to zero-padded 512x512 bf16 ----------------
__global__ __launch_bounds__(256) void k_pk(const float* __restrict__ Af, const float* __restrict__ A2,
                                            u16* __restrict__ Abf, u16* __restrict__ A2bf) {
  int i = blockIdx.x * 256 + threadIdx.x;
  if (i >= 262144) return;
  int r = i >> 9, v = i & 511;
  bool in = (r < 500) && (v < 500);
  Abf[i]  = f2b(in ? Af[r * 500 + v] : 0.f);
  A2bf[i] = f2b(in ? A2[r * 500 + v] : 0.f);
}

// ---------------- K0c: folded frontend weights (te1 folded into q/k/v; lino folded into te2) ----
// WT float layout:
//   c1T   [0,1024)      : [i*32+c]            = c1W[c*32+i]
//   qkF   [1024,7168)   : u32 [(c*3+tap)*64+o] = pk2(sum_i qW[o,i,tap]*te1W[i,c],
//                                                    sum_i kW[o,i,tap]*te1W[i,c])
//   bias6 [7168,7552)   : Cq[64],Ck[64],E0q[64],E0k[64],E2q[64],E2k[64]
//   vT    [7552,9600)   : [c*64+o]            = sum_i lvW[o,i]*te1W[i,c]
//   bv    [9600,9664)   : lvB[o] + sum_i lvW[o,i]*te1B[i]
//   otT   [9664,11712)  : [j*32+c]            = sum_o te2W[c,o]*loW[o,j]
//   bot   [11712,11744) : te2B[c] + sum_o te2W[c,o]*loB[o]
// WBu (separate buffer): mlpW bf16 B-frag pack [kt][ct][lane][j], 10240 u16
__global__ __launch_bounds__(256) void k_wprep(const float* __restrict__ Wf, float* __restrict__ WT,
                                               u16* __restrict__ WBu) {
  int i = blockIdx.x * 256 + threadIdx.x;
  if (i < 1024) {
    WT[i] = Wf[(i & 31) * 32 + (i >> 5)];
  } else if (i < 7168) {
    int j2 = i - 1024;
    int o = j2 & 63, ct = j2 >> 6;
    int c = ct / 3, tap = ct - c * 3;
    float sq = 0.f, sk = 0.f;
    for (int i2 = 0; i2 < 64; ++i2) {
      float te = Wf[1056 + i2 * 32 + c];
      sq += Wf[3168 + o * 192 + i2 * 3 + tap] * te;
      sk += Wf[15520 + o * 192 + i2 * 3 + tap] * te;
    }
    ((u32*)WT)[i] = pk2(sq, sk);
  } else if (i < 7552) {
    int j2 = i - 7168;
    int f = j2 >> 6, o = j2 & 63;
    int wbase = (f & 1) ? 15520 : 3168;
    float S0 = 0.f, S1 = 0.f, S2 = 0.f;
    for (int i2 = 0; i2 < 64; ++i2) {
      float tb = Wf[3104 + i2];
      S0 += Wf[wbase + o * 192 + i2 * 3 + 0] * tb;
      S1 += Wf[wbase + o * 192 + i2 * 3 + 1] * tb;
      S2 += Wf[wbase + o * 192 + i2 * 3 + 2] * tb;
    }
    float r;
    if (f == 0)      r = Wf[15456 + o] + S0 + S1 + S2;
    else if (f == 1) r = Wf[27808 + o] + S0 + S1 + S2;
    else if (f < 4)  r = S0;
    else             r = S2;
    WT[i] = r;
  } else if (i < 9600) {
    int j2 = i - 7552;
    int c = j2 >> 6, o = j2 & 63;
    float s = 0.f;
    for (int i2 = 0; i2 < 64; ++i2)
      s += Wf[27872 + o * 64 + i2] * Wf[1056 + i2 * 32 + c];
    WT[i] = s;
  } else if (i < 9664) {
    int o = i - 9600;
    float s = Wf[31968 + o];
    for (int i2 = 0; i2 < 64; ++i2)
      s += Wf[27872 + o * 64 + i2] * Wf[3104 + i2];
    WT[i] = s;
  } else if (i < 11712) {
    int j2 = i - 9664;
    int jj = j2 >> 5, c = j2 & 31;
    float s = 0.f;
    for (int o2 = 0; o2 < 64; ++o2)
      s += Wf[36192 + c * 64 + o2] * Wf[32032 + o2 * 64 + jj];
    WT[i] = s;
  } else if (i < 11744) {
    int c = i - 11712;
    float s = Wf[38240 + c];
    for (int o2 = 0; o2 < 64; ++o2)
      s += Wf[36192 + c * 64 + o2] * Wf[36128 + o2];
    WT[i] = s;
  } else if (i < 21984) {
    int j2 = i - 11744;
    int j = j2 & 7, lanev = (j2 >> 3) & 63, ct = (j2 >> 9) & 3, kt = j2 >> 11;
    int qv = lanev >> 4, lnv = lanev & 15;
    int o = ct * 16 + lnv, k = kt * 32 + qv * 8 + j;
    WBu[j2] = f2b(Wf[38272 + o * 160 + k]);
  }
}

// ---------------- K1: frontend (folded), one (b,n) pair per WAVE, zero block barriers ----------------
// lane = output channel (64). Per-wave LDS arena (1920 floats):
//   x     [0,384)    rows c*12, dead after qkv
//   qB16  u32 [0,320)   (overwrites x after qkv; bf16 pairs, stride 5 u32/row)
//   k     [320,1088) rows stride 12 (fp32, b128-aligned)
//   P     [1088,1888) rows stride 10 (fp32)
//   o     [0,768)    rows stride 12 (after PV; q/k dead)
// q,k,v computed DIRECTLY from x via folded weights (te1 eliminated);
// lino folded into te2 (otT). In-order per-wave LDS + wave_barrier only.
__global__ __launch_bounds__(256, 5) void k_front3(
    const float* __restrict__ xf, const float* __restrict__ WT,
    const float* __restrict__ c1B,
    float* __restrict__ h3x, float* __restrict__ res6)
{
  __shared__ __align__(16) float arena[4][1920];
  int tid = threadIdx.x;
  int wave = tid >> 6, lane = tid & 63;
  float* Aw = arena[wave];
  int pair = blockIdx.x * 4 + wave;
  int b = pair / 500, n = pair - b * 500;

  const float* c1T  = WT;
  const u32*   qkF  = (const u32*)(WT + 1024);
  const float* bCq  = WT + 7168;
  const float* bCk  = WT + 7232;
  const float* bE0q = WT + 7296;
  const float* bE0k = WT + 7360;
  const float* bE2q = WT + 7424;
  const float* bE2k = WT + 7488;
  const float* vT   = WT + 7552;
  const float* bvp  = WT + 9600;
  const float* otT  = WT + 9664;
  const float* botp = WT + 11712;

  // ---- x -> LDS rows [c*12 + t]
  {
    int c0 = lane >> 1, hf = (lane & 1) * 5;
    const float* xp = xf + ((b * 32 + c0) * 500 + n) * 10 + hf;
    float* dst = Aw + c0 * 12 + hf;
#pragma unroll
    for (int k2 = 0; k2 < 5; ++k2) dst[k2] = xp[k2];
  }
  __builtin_amdgcn_wave_barrier();

  int cl = lane & 31, th = lane >> 5;

  // ---- residual: lane=(c, th), 3 time outputs each
  {
    float r0 = c1B[cl], r1 = r0, r2 = r0;
#pragma unroll 4
    for (int i = 0; i < 32; ++i) {
      float w = c1T[i * 32 + cl];
      const float* xr = Aw + i * 12 + 4 + th * 3;
      r0 += w * xr[0]; r1 += w * xr[1]; r2 += w * xr[2];
    }
    float* rp = res6 + ((b * 32 + cl) * 500 + n) * 6 + th * 3;
    rp[0] = r0; rp[1] = r1; rp[2] = r2;
  }

  // ---- q,k,v directly from x: lane = o; 66 FMA per c-iteration, broadcast x rows
  float qr[10], kr[10], vr[10];
  {
    float cq = bCq[lane], ck = bCk[lane], bv = bvp[lane];
#pragma unroll
    for (int t = 0; t < 10; ++t) { qr[t] = cq; kr[t] = ck; vr[t] = bv; }
    qr[0] -= bE0q[lane]; kr[0] -= bE0k[lane];
    qr[9] -= bE2q[lane]; kr[9] -= bE2k[lane];
    const u32* qp0 = qkF + lane;
    const float* vp0 = vT + lane;
#pragma unroll 2
    for (int c = 0; c < 32; ++c) {
      const float* xr = Aw + c * 12;
      float4 ha = *(const float4*)xr;
      float4 hb = *(const float4*)(xr + 4);
      float2 hc = *(const float2*)(xr + 8);
      u32 u0 = qp0[c * 192];
      u32 u1 = qp0[c * 192 + 64];
      u32 u2 = qp0[c * 192 + 128];
      float wv = vp0[c * 64];
      float q0 = lopart(u0), q1 = lopart(u1), q2 = lopart(u2);
      float k0 = hipart(u0), k1 = hipart(u1), k2v = hipart(u2);
      float hh[10] = {ha.x, ha.y, ha.z, ha.w, hb.x, hb.y, hb.z, hb.w, hc.x, hc.y};
#pragma unroll
      for (int t = 0; t < 10; ++t) { float c_ = hh[t]; qr[t] += q1 * c_; kr[t] += k1 * c_; vr[t] += wv * c_; }
#pragma unroll
      for (int t = 1; t < 10; ++t) { float c_ = hh[t - 1]; qr[t] += q0 * c_; kr[t] += k0 * c_; }
#pragma unroll
      for (int t = 0; t < 9; ++t) { float c_ = hh[t + 1]; qr[t] += q2 * c_; kr[t] += k2v * c_; }
    }
  }
  __builtin_amdgcn_wave_barrier();
  // spill q (bf16 pairs, stride 5 u32) and k (fp32, stride 12)
  {
    u32* qu = (u32*)Aw + lane * 5;
#pragma unroll
    for (int m = 0; m < 5; ++m) qu[m] = pk2(qr[2 * m], qr[2 * m + 1]);
    float* kp = Aw + 320 + lane * 12;
    *(float4*)kp       = make_float4(kr[0], kr[1], kr[2], kr[3]);
    *(float4*)(kp + 4) = make_float4(kr[4], kr[5], kr[6], kr[7]);
    *(float2*)(kp + 8) = make_float2(kr[8], kr[9]);
  }
  __builtin_amdgcn_wave_barrier();

  // ---- scores + softmax: 80 (head,row) rows over 2 passes; P -> [1088,1888)
  {
    const u32* qb = (const u32*)Aw;
#pragma unroll
    for (int pass = 0; pass < 2; ++pass) {
      int row = pass * 64 + lane;
      if (row < 80) {
        int h8 = (row / 10) * 8, r = row - (row / 10) * 10;
        int rm = r >> 1, rs = r & 1;
        float sv[10];
#pragma unroll
        for (int s = 0; s < 10; ++s) sv[s] = 0.f;
#pragma unroll 2
        for (int d = 0; d < 8; ++d) {
          int jj = h8 + d;
          u32 qu = qb[jj * 5 + rm];
          float qv = rs ? hipart(qu) : lopart(qu);
          const float* kp2 = Aw + 320 + jj * 12;
          float4 ka = *(const float4*)kp2;
          float4 kb = *(const float4*)(kp2 + 4);
          float2 kc = *(const float2*)(kp2 + 8);
          sv[0] += qv * ka.x; sv[1] += qv * ka.y; sv[2] += qv * ka.z; sv[3] += qv * ka.w;
          sv[4] += qv * kb.x; sv[5] += qv * kb.y; sv[6] += qv * kb.z; sv[7] += qv * kb.w;
          sv[8] += qv * kc.x; sv[9] += qv * kc.y;
        }
        const float sc_ = 0.35355339059327373f;
        float mx = sv[0];
#pragma unroll
        for (int s = 1; s < 10; ++s) mx = fmaxf(mx, sv[s]);
        float tot = 0.f, ev[10];
#pragma unroll
        for (int s = 0; s < 10; ++s) { ev[s] = expf((sv[s] - mx) * sc_); tot += ev[s]; }
        float inv = 1.f / tot;
        float* pp = Aw + 1088 + row * 10;
#pragma unroll
        for (int s = 0; s < 10; ++s) pp[s] = ev[s] * inv;
      }
    }
  }
  __builtin_amdgcn_wave_barrier();

  // ---- PV: lane = j (head h=j>>3), v in regs, P broadcast per 8-lane group; o -> [0,768)
  {
    const float* pb = Aw + 1088 + (lane >> 3) * 100;
    float orr[10];
#pragma unroll
    for (int t = 0; t < 10; ++t) {
      const float* pr = pb + t * 10;
      float a = 0.f;
#pragma unroll
      for (int s = 0; s < 10; ++s) a += pr[s] * vr[s];
      orr[t] = a;
    }
    float* op = Aw + lane * 12;
    *(float4*)op       = make_float4(orr[0], orr[1], orr[2], orr[3]);
    *(float4*)(op + 4) = make_float4(orr[4], orr[5], orr[6], orr[7]);
    *(float2*)(op + 8) = make_float2(orr[8], orr[9]);
  }
  __builtin_amdgcn_wave_barrier();

  // ---- fused lino+te2 + h3x store: lane = (c, th), 5 t's each
  {
    float bt2 = botp[cl];
    float a5[5];
#pragma unroll
    for (int k2 = 0; k2 < 5; ++k2) a5[k2] = bt2;
    const float* tp0 = otT + cl;
    const float* base = Aw + th * 5;
#pragma unroll 2
    for (int j = 0; j < 64; ++j) {
      float w = tp0[j * 32];
      const float* lp = base + j * 12;
#pragma unroll
      for (int k2 = 0; k2 < 5; ++k2) a5[k2] += w * lp[k2];
    }
    int t0 = th * 5;
#pragma unroll
    for (int k2 = 0; k2 < 5; ++k2)
      h3x[((b * 10 + t0 + k2) * 500 + n) * 32 + cl] = a5[k2];
  }
}

// ---------------- K2: MFMA z1 = A @ XT, z2 = A2 @ XT ----------------
__global__ __launch_bounds__(256, 4) void k_z12m(const float* __restrict__ h3x,
    const u16* __restrict__ Abf, const u16* __restrict__ A2bf,
    float* __restrict__ z1x, float* __restrict__ z2x) {
  __shared__ u32 xlsT[8192];     // [n][half-row] pairs, swizzled (32 KB)
  int tid = threadIdx.x, bt = blockIdx.x;
  const float* src = h3x + bt * 16000;
  for (int i = tid; i < 8192; i += 256) {
    int n = i & 31, h = i >> 5;
    int r0 = 2 * h;
    float v0 = (r0 < 500) ? src[r0 * 32 + n] : 0.f;
    float v1 = (r0 + 1 < 500) ? src[(r0 + 1) * 32 + n] : 0.f;
    xlsT[n * 256 + (((h & 0xFC) ^ ((n & 15) << 2)) | (h & 3))] = pk2(v0, v1);
  }
  __syncthreads();
  int lane = tid & 63, wave = tid >> 6;
  int q = lane >> 4, ln = lane & 15;
  int rbase = blockIdx.y * 64 + wave * 16;
  const u32* Au = (const u32*)Abf;
  const u32* A2u = (const u32*)A2bf;
  int arow = (rbase + ln) * 256;
  union F8 { u32 u[4]; short8 s; };
  floatx4 acc1[2] = {{0.f,0.f,0.f,0.f},{0.f,0.f,0.f,0.f}};
  floatx4 acc2[2] = {{0.f,0.f,0.f,0.f},{0.f,0.f,0.f,0.f}};
  for (int c2 = 0; c2 < 16; ++c2) {
    int hb = c2 * 16 + q * 4;         // aligned half-row base for this quad's k-slice
    F8 a1f, a2f;
#pragma unroll
    for (int i2 = 0; i2 < 4; ++i2) {
      a1f.u[i2] = Au[arow + hb + i2];
      a2f.u[i2] = A2u[arow + hb + i2];
    }
#pragma unroll
    for (int t2 = 0; t2 < 2; ++t2) {
      int n = t2 * 16 + ln;
      int baseT = n * 256 + (hb ^ ((n & 15) << 2));
      F8 bf;
#pragma unroll
      for (int i2 = 0; i2 < 4; ++i2) bf.u[i2] = xlsT[baseT + i2];
      acc1[t2] = __builtin_amdgcn_mfma_f32_16x16x32_bf16(a1f.s, bf.s, acc1[t2], 0, 0, 0);
      acc2[t2] = __builtin_amdgcn_mfma_f32_16x16x32_bf16(a2f.s, bf.s, acc2[t2], 0, 0, 0);
    }
  }
  int outb = bt * 16000;
#pragma unroll
  for (int t2 = 0; t2 < 2; ++t2) {
#pragma unroll
    for (int i2 = 0; i2 < 4; ++i2) {
      int r = rbase + q * 4 + i2;
      if (r < 500) {
        z1x[outb + r * 32 + t2 * 16 + ln] = acc1[t2][i2];
        z2x[outb + r * 32 + t2 * 16 + ln] = acc2[t2][i2];
      }
    }
  }
}

// ---------------- K3: MFMA fused attention: out = softmax(K K^T / sqrt(32)) @ V ----------------
__global__ __launch_bounds__(256, 2) void k_attn2(const float* __restrict__ keys,
                                                  const float* __restrict__ vals,
                                                  float* __restrict__ outp) {
  __shared__ u32 xls[8192];        // 512 rows x 16 u32 bf16-pairs, swizzled (32 KB)
  __shared__ u32 pch[4][272];      // per-wave P chunk: 16 x 17 u32 (4.25 KB)
  int tid = threadIdx.x, bt = blockIdx.x;
  const float* kb = keys + bt * 16000;
  for (int i = tid; i < 8192; i += 256) {
    int r = i >> 4, cu = i & 15;
    u32 u = 0;
    if (r < 500) {
      float2 g = *(const float2*)(kb + r * 32 + cu * 2);
      u = pk2(g.x, g.y);
    }
    xls[(r << 4) | (cu ^ (r & 15))] = u;
  }
  __syncthreads();
  int lane = tid & 63, wave = tid >> 6;
  int q = lane >> 4, ln = lane & 15;
  int rbase = blockIdx.y * 64 + wave * 16;
  union F8 { u32 u[4]; short8 s; };
  F8 af;
  {
    int r = rbase + ln;
#pragma unroll
    for (int i2 = 0; i2 < 4; ++i2)
      af.u[i2] = xls[(r << 4) | ((q * 4 + i2) ^ (r & 15))];
  }
  floatx4 acc[32];
#pragma unroll
  for (int ct = 0; ct < 32; ++ct) {
    int r2 = ct * 16 + ln;
    F8 bf;
#pragma unroll
    for (int i2 = 0; i2 < 4; ++i2)
      bf.u[i2] = xls[(r2 << 4) | ((q * 4 + i2) ^ (r2 & 15))];
    acc[ct] = __builtin_amdgcn_mfma_f32_16x16x32_bf16(af.s, bf.s,
              (floatx4){0.f, 0.f, 0.f, 0.f}, 0, 0, 0);
  }
  if (ln >= 4) {
#pragma unroll
    for (int i2 = 0; i2 < 4; ++i2) acc[31][i2] = -1e30f;
  }
  const float sc = 0.17677669529663687f;
  float inv[4];
#pragma unroll
  for (int i2 = 0; i2 < 4; ++i2) {
    float m = -1e30f;
#pragma unroll
    for (int ct = 0; ct < 32; ++ct) m = fmaxf(m, acc[ct][i2]);
#pragma unroll
    for (int d = 1; d < 16; d <<= 1) m = fmaxf(m, __shfl_xor(m, d));
    float s = 0.f;
#pragma unroll
    for (int ct = 0; ct < 32; ++ct) {
      float e = expf((acc[ct][i2] - m) * sc);
      acc[ct][i2] = e; s += e;
    }
#pragma unroll
    for (int d = 1; d < 16; d <<= 1) s += __shfl_xor(s, d);
    inv[i2] = 1.f / s;
  }
  const float* vb = vals + bt * 16000;
  floatx4 zacc[2] = {{0.f,0.f,0.f,0.f},{0.f,0.f,0.f,0.f}};
  u32* myp = pch[wave];
  u16* pw = (u16*)myp;
  for (int c2 = 0; c2 < 16; ++c2) {
#pragma unroll
    for (int t2 = 0; t2 < 2; ++t2) {
      int ct = c2 * 2 + t2;
#pragma unroll
      for (int i2 = 0; i2 < 4; ++i2)
        pw[(q * 4 + i2) * 34 + t2 * 16 + ln] = f2b(acc[ct][i2] * inv[i2]);
    }
    __syncthreads();
    F8 pa;
#pragma unroll
    for (int i2 = 0; i2 < 4; ++i2) pa.u[i2] = myp[ln * 17 + q * 4 + i2];
    int k0 = c2 * 32 + q * 8;
#pragma unroll
    for (int t2 = 0; t2 < 2; ++t2) {
      int n = t2 * 16 + ln;
      short8 bs;
#pragma unroll
      for (int j = 0; j < 8; ++j) {
        float v = vb[(k0 + j) * 32 + n];
        bs[j] = (short)(__float_as_uint(v) >> 16);
      }
      zacc[t2] = __builtin_amdgcn_mfma_f32_16x16x32_bf16(pa.s, bs, zacc[t2], 0, 0, 0);
    }
    __syncthreads();
  }
  int outb = bt * 16000;
#pragma unroll
  for (int t2 = 0; t2 < 2; ++t2) {
#pragma unroll
    for (int i2 = 0; i2 < 4; ++i2) {
      int r = rbase + q * 4 + i2;
      if (r < 500) outp[outb + r * 32 + t2 * 16 + ln] = zacc[t2][i2];
    }
  }
}

// ---------------- K4: MFMA mlp + gate + fused ct1 -> g2 ----------------
__global__ __launch_bounds__(256, 2) void k_gate(
    const float* __restrict__ h3x, const float* __restrict__ z1x, const float* __restrict__ z2x,
    const float* __restrict__ z3x, const float* __restrict__ z4x,
    const u32* __restrict__ WBq, const float* __restrict__ mlpB,
    const float* __restrict__ ct1W, const float* __restrict__ ct1B,
    float* __restrict__ g2w)
{
  __shared__ u32 wlds[5120];       // 20 KB: 20 B-frags x 64 lanes x 4 u32
  int tid = threadIdx.x;
  for (int i = tid; i < 5120; i += 256) wlds[i] = WBq[i];
  __syncthreads();
  int lane = tid & 63, wave = tid >> 6;
  int q = lane >> 4, ln = lane & 15;
  int b = blockIdx.y;
  int n0 = blockIdx.x * 32 + wave * 8;
  int nA = n0 + (ln & 7);          // A-row n for this lane
  int tAb = ln >> 3;               // A-row t_local (0/1)
  int nD = n0 + (q & 1) * 4;       // D-row n base (n = nD + i)
  int tDb = q >> 1;                // D-row t_local
  float g2a[4][2][6];
#pragma unroll
  for (int i = 0; i < 4; ++i)
#pragma unroll
    for (int ch = 0; ch < 2; ++ch)
#pragma unroll
      for (int s = 0; s < 6; ++s) g2a[i][ch][s] = 0.f;
  float bias[4];
#pragma unroll
  for (int ct = 0; ct < 4; ++ct) bias[ct] = mlpB[ct * 16 + ln];
  union F8 { u32 u[4]; short8 s; };
  for (int tile = 0; tile < 5; ++tile) {
    int tA = tile * 2 + tAb;
    int offA = (((b * 10 + tA) * 500) + nA) * 32 + q * 8;
    floatx4 acc[4];
#pragma unroll
    for (int ct = 0; ct < 4; ++ct) acc[ct] = (floatx4){bias[ct], bias[ct], bias[ct], bias[ct]};
#pragma unroll
    for (int kt = 0; kt < 5; ++kt) {
      const float* sp = kt == 0 ? h3x : kt == 1 ? z1x : kt == 2 ? z2x : kt == 3 ? z3x : z4x;
      float4 a0 = *(const float4*)(sp + offA);
      float4 a1 = *(const float4*)(sp + offA + 4);
      F8 af;
      af.u[0] = cvtpk(a0.x, a0.y);
      af.u[1] = cvtpk(a0.z, a0.w);
      af.u[2] = cvtpk(a1.x, a1.y);
      af.u[3] = cvtpk(a1.z, a1.w);
#pragma unroll
      for (int ct = 0; ct < 4; ++ct) {
        F8 bfr;
        const u32* wp = wlds + (((kt * 4 + ct) << 6) + lane) * 4;
#pragma unroll
        for (int i2 = 0; i2 < 4; ++i2) bfr.u[i2] = wp[i2];
        acc[ct] = __builtin_amdgcn_mfma_f32_16x16x32_bf16(af.s, bfr.s, acc[ct], 0, 0, 0);
      }
    }
    int tD = tile * 2 + tDb;
    float c6[6];
#pragma unroll
    for (int s = 0; s < 6; ++s) c6[s] = ct1W[s * 10 + tD];
#pragma unroll
    for (int i = 0; i < 4; ++i) {
      float e0 = __expf(2.f * acc[0][i]);
      float g0 = ((e0 - 1.f) / (e0 + 1.f)) * (1.f / (1.f + __expf(-acc[2][i])));
      float e1 = __expf(2.f * acc[1][i]);
      float g1 = ((e1 - 1.f) / (e1 + 1.f)) * (1.f / (1.f + __expf(-acc[3][i])));
#pragma unroll
      for (int s = 0; s < 6; ++s) {
        g2a[i][0][s] += g0 * c6[s];
        g2a[i][1][s] += g1 * c6[s];
      }
    }
  }
  // combine even-t (q=0,1) and odd-t (q=2,3) partial sums: lane pair = lane ^ 32
#pragma unroll
  for (int i = 0; i < 4; ++i)
#pragma unroll
    for (int ch = 0; ch < 2; ++ch)
#pragma unroll
      for (int s = 0; s < 6; ++s)
        g2a[i][ch][s] += __shfl_xor(g2a[i][ch][s], 32);
  if (q < 2) {
#pragma unroll
    for (int i = 0; i < 4; ++i) {
      int n = nD + i;
      if (n < 500) {
#pragma unroll
        for (int ch = 0; ch < 2; ++ch) {
          int c = ln + ch * 16;
          float* gp = g2w + ((b * 32 + c) * 500 + n) * 6;
#pragma unroll
          for (int s = 0; s < 6; ++s) gp[s] = g2a[i][ch][s] + ct1B[s];
        }
      }
    }
  }
}

// ---------------- K4b: f1 ----------------
__global__ __launch_bounds__(256) void k_f1n(const float* __restrict__ g2w,
                                             const float* __restrict__ tc1W,
                                             float* __restrict__ f1w) {
  int i = blockIdx.x * 256 + threadIdx.x;
  if (i >= 48000) return;
  int b = i / 3000, rem = i - b * 3000, s = rem / 500, n = rem - s * 500;
  float a = 0.f;
  for (int c = 0; c < 32; ++c) a += g2w[((b * 32 + c) * 500 + n) * 6 + s] * tc1W[c];
  f1w[(b * 6 + s) * 500 + n] = a;
}

// ---------------- K5a: f2 ----------------
__global__ __launch_bounds__(64) void k_f2(const float* __restrict__ g2w,
                                           const float* __restrict__ c2W, float* __restrict__ f2w) {
  int b = blockIdx.x >> 5, c = blockIdx.x & 31, lane = threadIdx.x;
  float acc[6];
#pragma unroll
  for (int t = 0; t < 6; ++t) acc[t] = 0.f;
  for (int n = lane; n < 500; n += 64) {
    float w = c2W[n];
    const float* gp = g2w + ((b * 32 + c) * 500 + n) * 6;
#pragma unroll
    for (int t = 0; t < 6; ++t) acc[t] += w * gp[t];
  }
#pragma unroll
  for (int t = 0; t < 6; ++t)
    for (int off = 32; off; off >>= 1) acc[t] += __shfl_xor(acc[t], off);
  if (lane == 0) {
#pragma unroll
    for (int t = 0; t < 6; ++t) f2w[(b * 32 + c) * 6 + t] = acc[t];
  }
}

// ---------------- K5b: per-b TATT ----------------
__global__ __launch_bounds__(256) void k_tatt(
    const float* __restrict__ f1w, const float* __restrict__ tatw,
    const float* __restrict__ f2w, const float* __restrict__ tatb, const float* __restrict__ tatv,
    float* __restrict__ lg2w)
{
  __shared__ float mid[192];
  __shared__ float lgt[36];
  int b = blockIdx.x, tid = threadIdx.x;
  if (tid < 192) {
    int t = tid >> 5, c = tid & 31;
    float a = 0.f;
    const float* f1p = f1w + (b * 6 + t) * 500;
    for (int n = 0; n < 500; ++n) a += f1p[n] * tatw[n * 32 + c];
    mid[t * 32 + c] = a;
  }
  __syncthreads();
  if (tid < 36) {
    int t = tid / 6, s = tid - t * 6;
    float a = tatb[t * 6 + s];
    for (int c = 0; c < 32; ++c) a += mid[t * 32 + c] * f2w[(b * 32 + c) * 6 + s];
    lgt[t * 6 + s] = 1.f / (1.f + expf(-a));
  }
  __syncthreads();
  if (tid < 36) {
    int p = tid / 6, s = tid - p * 6;
    float a = 0.f;
#pragma unroll
    for (int t2 = 0; t2 < 6; ++t2) a += tatv[p * 6 + t2] * lgt[t2 * 6 + s];
    lg2w[(b * 6 + p) * 6 + s] = a;
  }
}

// ---------------- K5c: BN1 + softmax -> Tc ----------------
__global__ __launch_bounds__(128) void k_coefs(const float* __restrict__ lg2w,
    const float* __restrict__ bn1g, const float* __restrict__ bn1b, float* __restrict__ tcw) {
  __shared__ float mu[6], iv[6], gg[6], bb[6];
  int tid = threadIdx.x;
  if (tid < 6) {
    float s = 0.f, sq = 0.f;
    for (int b = 0; b < 16; ++b)
      for (int q = 0; q < 6; ++q) {
        float v = lg2w[(b * 6 + q) * 6 + tid];
        s += v; sq += v * v;
      }
    float m = s / 96.f;
    mu[tid] = m;
    iv[tid] = rsqrtf(sq / 96.f - m * m + 1e-5f);
    gg[tid] = bn1g[tid]; bb[tid] = bn1b[tid];
  }
  __syncthreads();
  for (int idx = tid; idx < 96; idx += 128) {
    int b = idx / 6, q = idx - b * 6;
    float v[6], mx = -1e30f;
#pragma unroll
    for (int l = 0; l < 6; ++l) {
      v[l] = (lg2w[(b * 6 + q) * 6 + l] - mu[l]) * iv[l] * gg[l] + bb[l];
      mx = fmaxf(mx, v[l]);
    }
    float tot = 0.f;
#pragma unroll
    for (int l = 0; l < 6; ++l) { v[l] = expf(v[l] - mx); tot += v[l]; }
    float inv = 1.f / tot;
#pragma unroll
    for (int l = 0; l < 6; ++l) tcw[(b * 6 + l) * 6 + q] = v[l] * inv;
  }
}

// ---------------- K6a: xo = leaky(g2@Tc)+res6, per-c sum/sumsq ----------------
__global__ __launch_bounds__(256) void k_xo(const float* __restrict__ g2w,
    const float* __restrict__ res6, const float* __restrict__ tcw,
    float* __restrict__ xow, float* __restrict__ stats) {
  __shared__ float Tcl[36];
  __shared__ float redS[32][8], redQ[32][8];
  int b = blockIdx.x, chunk = blockIdx.y, tid = threadIdx.x;
  if (tid < 36) Tcl[tid] = tcw[b * 36 + tid];
  __syncthreads();
  int c = tid & 31, sub = tid >> 5;
  int n0 = chunk * 50;
  float s = 0.f, sq = 0.f;
  for (int idx = sub; idx < 300; idx += 8) {
    int nl = idx / 6, q = idx - nl * 6;
    int n = n0 + nl;
    int base = ((b * 32 + c) * 500 + n) * 6;
    const float* gp = g2w + base;
    float xv = 0.f;
#pragma unroll
    for (int l = 0; l < 6; ++l) xv += gp[l] * Tcl[l * 6 + q];
    xv = xv > 0.f ? xv : 0.01f * xv;
    xv += res6[base + q];
    xow[base + q] = xv;
    s += xv; sq += xv * xv;
  }
  redS[c][sub] = s; redQ[c][sub] = sq;
  __syncthreads();
  if (sub == 0) {
    float ts = 0.f, tq = 0.f;
#pragma unroll
    for (int k = 0; k < 8; ++k) { ts += redS[c][k]; tq += redQ[c][k]; }
    atomicAdd(&stats[c], ts);
    atomicAdd(&stats[32 + c], tq);
  }
}

// ---------------- K6b: BN2 normalize -> FP32 out ----------------
__global__ __launch_bounds__(256) void k_out(const float* __restrict__ xow,
    const float* __restrict__ stats, const float* __restrict__ g2c, const float* __restrict__ b2c,
    float* __restrict__ out) {
  int base = (blockIdx.x * 256 + threadIdx.x) * 4;
#pragma unroll
  for (int k = 0; k < 4; ++k) {
    int i = base + k;
    int c = (i / 3000) & 31;
    float m = stats[c] * (1.f / 48000.f);
    float var = stats[32 + c] * (1.f / 48000.f) - m * m;
    out[i] = (xow[i] - m) * rsqrtf(var + 1e-5f) * g2c[c] + b2c[c];
  }
}

extern "C" void kernel_launch(void* const* d_in, const int* in_sizes, int n_in,
                              void* d_out, int out_size, void* d_ws, size_t ws_size,
                              hipStream_t stream)
{
  (void)in_sizes; (void)out_size;

  float* ws = (float*)d_ws;
  float* Af   = ws;                 // 250,000
  float* Wf   = Af + 250000;        // 65,536 (65,322 used)
  float* A2   = Wf + 65536;         // 250,000
  float* h3x  = A2 + 250000;        // 2,560,000 (B,T,N,32)
  float* z1x  = h3x + 2560000;
  float* z2x  = z1x + 2560000;
  float* z3x  = z2x + 2560000;
  float* z4x  = z3x + 2560000;
  float* res6 = z4x + 2560000;      // 1,536,000
  float* g2w  = res6 + 1536000;     // 1,536,000
  float* f1w  = g2w + 1536000;      // 48,000
  float* f2w  = f1w + 48000;        // 3,072
  float* lg2w = f2w + 3072;         // 576
  float* tcw  = lg2w + 576;         // 576
  float* stats= tcw + 576;          // 64
  int*   dtf  = (int*)(stats + 64); // 1 int
  float* xf   = z4x;                // x fp32 overlay: dead after k_front3, before k_attn2#2
  float* xow  = z1x;                // reuse z1 region after k_gate
  u16*   Abf  = (u16*)g2w;          // 512x512 bf16 A pack (g2w region dead until k_gate)
  u16*   A2bf = (u16*)(g2w + 131072); // 512x512 bf16 A2 pack
  float* WTp  = g2w + 262144;       // 11,744 folded-weight pack (dead before k_gate)
  u16*   WBu  = (u16*)f1w;          // 10,240 u16 mlpW B-frag pack (f1w region dead until k_f1n)
  if (ws_size < (size_t)16489952 * sizeof(float)) return;  // workspace guard

  // converted-weight offsets inside Wf (cumulative over dict inputs 2..28)
  const float* c1B  = Wf + 1024;
  const float* mlpB = Wf + 48512;
  const float* ct1W = Wf + 48576;
  const float* ct1B = Wf + 48636;
  const float* tc1W = Wf + 48642;
  const float* tc2W = Wf + 48674;
  const float* tatw = Wf + 49174;
  const float* tatb = Wf + 65174;
  const float* tatv = Wf + 65210;
  const float* bn1g = Wf + 65246;
  const float* bn1b = Wf + 65252;
  const float* bn2g = Wf + 65258;
  const float* bn2b = Wf + 65290;

  Ptrs ps;
  for (int i = 0; i < 29; ++i) ps.p[i] = (i < n_in) ? d_in[i] : d_in[0];

  hipMemsetAsync(stats, 0, 64 * sizeof(float), stream);
  k_resolve<<<dim3(1),     64, 0, stream>>>(ps.p[25], dtf);
  k_cvt  <<<dim3(1232),    256, 0, stream>>>(ps, dtf, Af, Wf);
  k_cvtx <<<dim3(10000),   256, 0, stream>>>(ps.p[0], dtf, xf);
  k_wprep<<<dim3(86),      256, 0, stream>>>(Wf, WTp, WBu);
  k_a2   <<<dim3(2, 63),   256, 0, stream>>>(Af, A2);
  k_pk   <<<dim3(1024),    256, 0, stream>>>(Af, A2, Abf, A2bf);
  k_front3<<<dim3(2000),   256, 0, stream>>>(xf, WTp, c1B, h3x, res6);
  k_z12m <<<dim3(160, 8),  256, 0, stream>>>(h3x, Abf, A2bf, z1x, z2x);
  k_attn2<<<dim3(160, 8),  256, 0, stream>>>(h3x, h3x, z3x);
  k_attn2<<<dim3(160, 8),  256, 0, stream>>>(h3x, z3x, z4x);
  k_gate <<<dim3(16, 16),  256, 0, stream>>>(h3x, z1x, z2x, z3x, z4x,
                                             (const u32*)WBu, mlpB, ct1W, ct1B, g2w);
  k_f1n  <<<dim3(188),     256, 0, stream>>>(g2w, tc1W, f1w);
  k_f2   <<<dim3(512),      64, 0, stream>>>(g2w, tc2W, f2w);
  k_tatt <<<dim3(16),      256, 0, stream>>>(f1w, tatw, f2w, tatb, tatv, lg2w);
  k_coefs<<<dim3(1),       128, 0, stream>>>(lg2w, bn1g, bn1b, tcw);
  k_xo   <<<dim3(16, 10),  256, 0, stream>>>(g2w, res6, tcw, xow, stats);
  k_out  <<<dim3(1500),    256, 0, stream>>>(xow, stats, bn2g, bn2b, (float*)d_out);
}

// Round 4
// 443.998 us; speedup vs baseline: 2.4646x; 1.2473x over previous
//
#include <hip/hip_runtime.h>

typedef unsigned short u16;
typedef unsigned int u32;

__device__ __forceinline__ float b2f(u16 v) { return __uint_as_float((u32)v << 16); }
__device__ __forceinline__ float lopart(u32 u) { return __uint_as_float(u << 16); }
__device__ __forceinline__ float hipart(u32 u) { return __uint_as_float(u & 0xffff0000u); }
__device__ __forceinline__ u16 f2b(float f) {
  u32 u = __float_as_uint(f);
  u32 r = u + 0x7fffu + ((u >> 16) & 1u);
  return (u16)(r >> 16);
}
__device__ __forceinline__ u32 pk2(float a, float b) {
  return (u32)f2b(a) | ((u32)f2b(b) << 16);
}
__device__ __forceinline__ u32 cvtpk(float lo, float hi) {
  u32 r;
  asm("v_cvt_pk_bf16_f32 %0, %1, %2" : "=v"(r) : "v"(lo), "v"(hi));
  return r;
}

struct Ptrs { const void* p[29]; };

typedef __attribute__((ext_vector_type(8))) short short8;
typedef __attribute__((ext_vector_type(4))) float floatx4;

// ---------------- K-2: dtype flag (bn1_g[0]: bf16 pair 0x3F803F80 vs fp32 0x3F800000) ----------------
__global__ void k_resolve(const void* __restrict__ g1, int* __restrict__ dtf) {
  if (threadIdx.x == 0) {
    u32 w = *(const u32*)g1;
    *dtf = ((w & 0xffffu) != 0) ? 1 : 0;
  }
}

// ---------------- K-1: convert A + all weights to fp32 (C-order identity; dict order) ----------------
__global__ __launch_bounds__(256) void k_cvt(Ptrs ps, const int* __restrict__ dtf,
                                             float* __restrict__ Af, float* __restrict__ Wf) {
  bool BF = *dtf != 0;
  int i = blockIdx.x * 256 + threadIdx.x;
  if (i < 250000) {
    const void* pA = ps.p[1];
    Af[i] = BF ? b2f(((const u16*)pA)[i]) : ((const float*)pA)[i];
    return;
  }
  int j = i - 250000;
  if (j >= 65322) return;
  const int SZ[27] = {1024,32,2048,64,12288,64,12288,64,4096,64,4096,64,2048,32,
                      10240,64,60,6,32,500,16000,36,36,6,6,32,32};
  int t = 0, off = 0;
#pragma unroll
  for (int k = 0; k < 27; ++k) {
    if (t == k && j >= off + SZ[k]) { off += SZ[k]; t = k + 1; }
  }
  const void* src = ps.p[2 + t];
  int l = j - off;
  Wf[j] = BF ? b2f(((const u16*)src)[l]) : ((const float*)src)[l];
}

// ---------------- K-0b: x -> fp32 (identity C-order) ----------------
__global__ __launch_bounds__(256) void k_cvtx(const void* __restrict__ x, const int* __restrict__ dtf,
                                              float* __restrict__ xf) {
  bool BF = *dtf != 0;
  int i = blockIdx.x * 256 + threadIdx.x;
  if (i < 2560000) xf[i] = BF ? b2f(((const u16*)x)[i]) : ((const float*)x)[i];
}

// ---------------- K0b: pack A to zero-padded 512x512 bf16 ----------------
__global__ __launch_bounds__(256) void k_pk(const float* __restrict__ Af, u16* __restrict__ Abf) {
  int i = blockIdx.x * 256 + threadIdx.x;
  if (i >= 262144) return;
  int r = i >> 9, v = i & 511;
  bool in = (r < 500) && (v < 500);
  Abf[i] = f2b(in ? Af[r * 500 + v] : 0.f);
}

// ---------------- K0m: MFMA A2 = A @ A (bf16 in/out, fp32 accumulate) ----------------
// Same structure as k_z12m: stage 32-col A^T tile in LDS (swizzled bf16 pairs),
// A-fragments stream from L2-hot Abf rows. Zero-padded rows/cols stay zero.
__global__ __launch_bounds__(256, 4) void k_a2m(const u16* __restrict__ Abf,
                                                u16* __restrict__ A2bf) {
  __shared__ u32 blsT[8192];     // [c][k-pair] swizzled (32 KB), c = local col
  int tid = threadIdx.x;
  int c0 = blockIdx.x * 32;
  for (int i = tid; i < 8192; i += 256) {
    int c = i & 31, h = i >> 5;
    int r0 = 2 * h;
    u32 lo = Abf[r0 * 512 + c0 + c];
    u32 hi = Abf[(r0 + 1) * 512 + c0 + c];
    blsT[c * 256 + (((h & 0xFC) ^ ((c & 15) << 2)) | (h & 3))] = lo | (hi << 16);
  }
  __syncthreads();
  int lane = tid & 63, wave = tid >> 6;
  int q = lane >> 4, ln = lane & 15;
  int rbase = blockIdx.y * 64 + wave * 16;
  const u32* Au = (const u32*)Abf;
  int arow = (rbase + ln) * 256;
  union F8 { u32 u[4]; short8 s; };
  floatx4 acc[2] = {{0.f,0.f,0.f,0.f},{0.f,0.f,0.f,0.f}};
  for (int c2 = 0; c2 < 16; ++c2) {
    int hb = c2 * 16 + q * 4;
    F8 af;
#pragma unroll
    for (int i2 = 0; i2 < 4; ++i2) af.u[i2] = Au[arow + hb + i2];
#pragma unroll
    for (int t2 = 0; t2 < 2; ++t2) {
      int c = t2 * 16 + ln;
      int baseT = c * 256 + (hb ^ ((c & 15) << 2));
      F8 bf;
#pragma unroll
      for (int i2 = 0; i2 < 4; ++i2) bf.u[i2] = blsT[baseT + i2];
      acc[t2] = __builtin_amdgcn_mfma_f32_16x16x32_bf16(af.s, bf.s, acc[t2], 0, 0, 0);
    }
  }
#pragma unroll
  for (int t2 = 0; t2 < 2; ++t2) {
#pragma unroll
    for (int i2 = 0; i2 < 4; ++i2) {
      int r = rbase + q * 4 + i2;
      A2bf[r * 512 + c0 + t2 * 16 + ln] = f2b(acc[t2][i2]);
    }
  }
}

// ---------------- K0c: folded frontend weights (te1 folded into q/k/v; lino folded into te2) ----
// WT float layout:
//   c1T   [0,1024)      : [i*32+c]            = c1W[c*32+i]
//   qkF   [1024,7168)   : u32 [(c*3+tap)*64+o] = pk2(sum_i qW[o,i,tap]*te1W[i,c],
//                                                    sum_i kW[o,i,tap]*te1W[i,c])
//   bias6 [7168,7552)   : Cq[64],Ck[64],E0q[64],E0k[64],E2q[64],E2k[64]
//   vT    [7552,9600)   : [c*64+o]            = sum_i lvW[o,i]*te1W[i,c]
//   bv    [9600,9664)   : lvB[o] + sum_i lvW[o,i]*te1B[i]
//   otT   [9664,11712)  : [j*32+c]            = sum_o te2W[c,o]*loW[o,j]
//   bot   [11712,11744) : te2B[c] + sum_o te2W[c,o]*loB[o]
// WBu (separate buffer): mlpW bf16 B-frag pack [kt][ct][lane][j], 10240 u16
__global__ __launch_bounds__(256) void k_wprep(const float* __restrict__ Wf, float* __restrict__ WT,
                                               u16* __restrict__ WBu) {
  int i = blockIdx.x * 256 + threadIdx.x;
  if (i < 1024) {
    WT[i] = Wf[(i & 31) * 32 + (i >> 5)];
  } else if (i < 7168) {
    int j2 = i - 1024;
    int o = j2 & 63, ct = j2 >> 6;
    int c = ct / 3, tap = ct - c * 3;
    float sq = 0.f, sk = 0.f;
    for (int i2 = 0; i2 < 64; ++i2) {
      float te = Wf[1056 + i2 * 32 + c];
      sq += Wf[3168 + o * 192 + i2 * 3 + tap] * te;
      sk += Wf[15520 + o * 192 + i2 * 3 + tap] * te;
    }
    ((u32*)WT)[i] = pk2(sq, sk);
  } else if (i < 7552) {
    int j2 = i - 7168;
    int f = j2 >> 6, o = j2 & 63;
    int wbase = (f & 1) ? 15520 : 3168;
    float S0 = 0.f, S1 = 0.f, S2 = 0.f;
    for (int i2 = 0; i2 < 64; ++i2) {
      float tb = Wf[3104 + i2];
      S0 += Wf[wbase + o * 192 + i2 * 3 + 0] * tb;
      S1 += Wf[wbase + o * 192 + i2 * 3 + 1] * tb;
      S2 += Wf[wbase + o * 192 + i2 * 3 + 2] * tb;
    }
    float r;
    if (f == 0)      r = Wf[15456 + o] + S0 + S1 + S2;
    else if (f == 1) r = Wf[27808 + o] + S0 + S1 + S2;
    else if (f < 4)  r = S0;
    else             r = S2;
    WT[i] = r;
  } else if (i < 9600) {
    int j2 = i - 7552;
    int c = j2 >> 6, o = j2 & 63;
    float s = 0.f;
    for (int i2 = 0; i2 < 64; ++i2)
      s += Wf[27872 + o * 64 + i2] * Wf[1056 + i2 * 32 + c];
    WT[i] = s;
  } else if (i < 9664) {
    int o = i - 9600;
    float s = Wf[31968 + o];
    for (int i2 = 0; i2 < 64; ++i2)
      s += Wf[27872 + o * 64 + i2] * Wf[3104 + i2];
    WT[i] = s;
  } else if (i < 11712) {
    int j2 = i - 9664;
    int jj = j2 >> 5, c = j2 & 31;
    float s = 0.f;
    for (int o2 = 0; o2 < 64; ++o2)
      s += Wf[36192 + c * 64 + o2] * Wf[32032 + o2 * 64 + jj];
    WT[i] = s;
  } else if (i < 11744) {
    int c = i - 11712;
    float s = Wf[38240 + c];
    for (int o2 = 0; o2 < 64; ++o2)
      s += Wf[36192 + c * 64 + o2] * Wf[36128 + o2];
    WT[i] = s;
  } else if (i < 21984) {
    int j2 = i - 11744;
    int j = j2 & 7, lanev = (j2 >> 3) & 63, ct = (j2 >> 9) & 3, kt = j2 >> 11;
    int qv = lanev >> 4, lnv = lanev & 15;
    int o = ct * 16 + lnv, k = kt * 32 + qv * 8 + j;
    WBu[j2] = f2b(Wf[38272 + o * 160 + k]);
  }
}

// ---------------- K1: frontend (folded), one (b,n) pair per WAVE, zero block barriers ----------------
// lane = output channel (64). Per-wave LDS arena (1920 floats):
//   x     [0,384)    rows c*12, dead after qkv
//   qB16  u32 [0,320)   (overwrites x after qkv; bf16 pairs, stride 5 u32/row)
//   k     [320,1088) rows stride 12 (fp32, b128-aligned)
//   P     [1088,1888) rows stride 10 (fp32)
//   o     [0,768)    rows stride 12 (after PV; q/k dead)
// q,k,v computed DIRECTLY from x via folded weights (te1 eliminated);
// lino folded into te2 (otT). In-order per-wave LDS + wave_barrier only.
__global__ __launch_bounds__(256, 5) void k_front3(
    const float* __restrict__ xf, const float* __restrict__ WT,
    const float* __restrict__ c1B,
    float* __restrict__ h3x, float* __restrict__ res6)
{
  __shared__ __align__(16) float arena[4][1920];
  int tid = threadIdx.x;
  int wave = tid >> 6, lane = tid & 63;
  float* Aw = arena[wave];
  int pair = blockIdx.x * 4 + wave;
  int b = pair / 500, n = pair - b * 500;

  const float* c1T  = WT;
  const u32*   qkF  = (const u32*)(WT + 1024);
  const float* bCq  = WT + 7168;
  const float* bCk  = WT + 7232;
  const float* bE0q = WT + 7296;
  const float* bE0k = WT + 7360;
  const float* bE2q = WT + 7424;
  const float* bE2k = WT + 7488;
  const float* vT   = WT + 7552;
  const float* bvp  = WT + 9600;
  const float* otT  = WT + 9664;
  const float* botp = WT + 11712;

  // ---- x -> LDS rows [c*12 + t]
  {
    int c0 = lane >> 1, hf = (lane & 1) * 5;
    const float* xp = xf + ((b * 32 + c0) * 500 + n) * 10 + hf;
    float* dst = Aw + c0 * 12 + hf;
#pragma unroll
    for (int k2 = 0; k2 < 5; ++k2) dst[k2] = xp[k2];
  }
  __builtin_amdgcn_wave_barrier();

  int cl = lane & 31, th = lane >> 5;

  // ---- residual: lane=(c, th), 3 time outputs each
  {
    float r0 = c1B[cl], r1 = r0, r2 = r0;
#pragma unroll 4
    for (int i = 0; i < 32; ++i) {
      float w = c1T[i * 32 + cl];
      const float* xr = Aw + i * 12 + 4 + th * 3;
      r0 += w * xr[0]; r1 += w * xr[1]; r2 += w * xr[2];
    }
    float* rp = res6 + ((b * 32 + cl) * 500 + n) * 6 + th * 3;
    rp[0] = r0; rp[1] = r1; rp[2] = r2;
  }

  // ---- q,k,v directly from x: lane = o; 66 FMA per c-iteration, broadcast x rows
  float qr[10], kr[10], vr[10];
  {
    float cq = bCq[lane], ck = bCk[lane], bv = bvp[lane];
#pragma unroll
    for (int t = 0; t < 10; ++t) { qr[t] = cq; kr[t] = ck; vr[t] = bv; }
    qr[0] -= bE0q[lane]; kr[0] -= bE0k[lane];
    qr[9] -= bE2q[lane]; kr[9] -= bE2k[lane];
    const u32* qp0 = qkF + lane;
    const float* vp0 = vT + lane;
#pragma unroll 2
    for (int c = 0; c < 32; ++c) {
      const float* xr = Aw + c * 12;
      float4 ha = *(const float4*)xr;
      float4 hb = *(const float4*)(xr + 4);
      float2 hc = *(const float2*)(xr + 8);
      u32 u0 = qp0[c * 192];
      u32 u1 = qp0[c * 192 + 64];
      u32 u2 = qp0[c * 192 + 128];
      float wv = vp0[c * 64];
      float q0 = lopart(u0), q1 = lopart(u1), q2 = lopart(u2);
      float k0 = hipart(u0), k1 = hipart(u1), k2v = hipart(u2);
      float hh[10] = {ha.x, ha.y, ha.z, ha.w, hb.x, hb.y, hb.z, hb.w, hc.x, hc.y};
#pragma unroll
      for (int t = 0; t < 10; ++t) { float c_ = hh[t]; qr[t] += q1 * c_; kr[t] += k1 * c_; vr[t] += wv * c_; }
#pragma unroll
      for (int t = 1; t < 10; ++t) { float c_ = hh[t - 1]; qr[t] += q0 * c_; kr[t] += k0 * c_; }
#pragma unroll
      for (int t = 0; t < 9; ++t) { float c_ = hh[t + 1]; qr[t] += q2 * c_; kr[t] += k2v * c_; }
    }
  }
  __builtin_amdgcn_wave_barrier();
  // spill q (bf16 pairs, stride 5 u32) and k (fp32, stride 12)
  {
    u32* qu = (u32*)Aw + lane * 5;
#pragma unroll
    for (int m = 0; m < 5; ++m) qu[m] = pk2(qr[2 * m], qr[2 * m + 1]);
    float* kp = Aw + 320 + lane * 12;
    *(float4*)kp       = make_float4(kr[0], kr[1], kr[2], kr[3]);
    *(float4*)(kp + 4) = make_float4(kr[4], kr[5], kr[6], kr[7]);
    *(float2*)(kp + 8) = make_float2(kr[8], kr[9]);
  }
  __builtin_amdgcn_wave_barrier();

  // ---- scores + softmax: 80 (head,row) rows over 2 passes; P -> [1088,1888)
  {
    const u32* qb = (const u32*)Aw;
#pragma unroll
    for (int pass = 0; pass < 2; ++pass) {
      int row = pass * 64 + lane;
      if (row < 80) {
        int h8 = (row / 10) * 8, r = row - (row / 10) * 10;
        int rm = r >> 1, rs = r & 1;
        float sv[10];
#pragma unroll
        for (int s = 0; s < 10; ++s) sv[s] = 0.f;
#pragma unroll 2
        for (int d = 0; d < 8; ++d) {
          int jj = h8 + d;
          u32 qu = qb[jj * 5 + rm];
          float qv = rs ? hipart(qu) : lopart(qu);
          const float* kp2 = Aw + 320 + jj * 12;
          float4 ka = *(const float4*)kp2;
          float4 kb = *(const float4*)(kp2 + 4);
          float2 kc = *(const float2*)(kp2 + 8);
          sv[0] += qv * ka.x; sv[1] += qv * ka.y; sv[2] += qv * ka.z; sv[3] += qv * ka.w;
          sv[4] += qv * kb.x; sv[5] += qv * kb.y; sv[6] += qv * kb.z; sv[7] += qv * kb.w;
          sv[8] += qv * kc.x; sv[9] += qv * kc.y;
        }
        const float sc_ = 0.35355339059327373f;
        float mx = sv[0];
#pragma unroll
        for (int s = 1; s < 10; ++s) mx = fmaxf(mx, sv[s]);
        float tot = 0.f, ev[10];
#pragma unroll
        for (int s = 0; s < 10; ++s) { ev[s] = expf((sv[s] - mx) * sc_); tot += ev[s]; }
        float inv = 1.f / tot;
        float* pp = Aw + 1088 + row * 10;
#pragma unroll
        for (int s = 0; s < 10; ++s) pp[s] = ev[s] * inv;
      }
    }
  }
  __builtin_amdgcn_wave_barrier();

  // ---- PV: lane = j (head h=j>>3), v in regs, P broadcast per 8-lane group; o -> [0,768)
  {
    const float* pb = Aw + 1088 + (lane >> 3) * 100;
    float orr[10];
#pragma unroll
    for (int t = 0; t < 10; ++t) {
      const float* pr = pb + t * 10;
      float a = 0.f;
#pragma unroll
      for (int s = 0; s < 10; ++s) a += pr[s] * vr[s];
      orr[t] = a;
    }
    float* op = Aw + lane * 12;
    *(float4*)op       = make_float4(orr[0], orr[1], orr[2], orr[3]);
    *(float4*)(op + 4) = make_float4(orr[4], orr[5], orr[6], orr[7]);
    *(float2*)(op + 8) = make_float2(orr[8], orr[9]);
  }
  __builtin_amdgcn_wave_barrier();

  // ---- fused lino+te2 + h3x store: lane = (c, th), 5 t's each
  {
    float bt2 = botp[cl];
    float a5[5];
#pragma unroll
    for (int k2 = 0; k2 < 5; ++k2) a5[k2] = bt2;
    const float* tp0 = otT + cl;
    const float* base = Aw + th * 5;
#pragma unroll 2
    for (int j = 0; j < 64; ++j) {
      float w = tp0[j * 32];
      const float* lp = base + j * 12;
#pragma unroll
      for (int k2 = 0; k2 < 5; ++k2) a5[k2] += w * lp[k2];
    }
    int t0 = th * 5;
#pragma unroll
    for (int k2 = 0; k2 < 5; ++k2)
      h3x[((b * 10 + t0 + k2) * 500 + n) * 32 + cl] = a5[k2];
  }
}

// ---------------- K2: MFMA z1 = A @ XT, z2 = A2 @ XT ----------------
__global__ __launch_bounds__(256, 4) void k_z12m(const float* __restrict__ h3x,
    const u16* __restrict__ Abf, const u16* __restrict__ A2bf,
    float* __restrict__ z1x, float* __restrict__ z2x) {
  __shared__ u32 xlsT[8192];     // [n][half-row] pairs, swizzled (32 KB)
  int tid = threadIdx.x, bt = blockIdx.x;
  const float* src = h3x + bt * 16000;
  for (int i = tid; i < 8192; i += 256) {
    int n = i & 31, h = i >> 5;
    int r0 = 2 * h;
    float v0 = (r0 < 500) ? src[r0 * 32 + n] : 0.f;
    float v1 = (r0 + 1 < 500) ? src[(r0 + 1) * 32 + n] : 0.f;
    xlsT[n * 256 + (((h & 0xFC) ^ ((n & 15) << 2)) | (h & 3))] = pk2(v0, v1);
  }
  __syncthreads();
  int lane = tid & 63, wave = tid >> 6;
  int q = lane >> 4, ln = lane & 15;
  int rbase = blockIdx.y * 64 + wave * 16;
  const u32* Au = (const u32*)Abf;
  const u32* A2u = (const u32*)A2bf;
  int arow = (rbase + ln) * 256;
  union F8 { u32 u[4]; short8 s; };
  floatx4 acc1[2] = {{0.f,0.f,0.f,0.f},{0.f,0.f,0.f,0.f}};
  floatx4 acc2[2] = {{0.f,0.f,0.f,0.f},{0.f,0.f,0.f,0.f}};
  for (int c2 = 0; c2 < 16; ++c2) {
    int hb = c2 * 16 + q * 4;         // aligned half-row base for this quad's k-slice
    F8 a1f, a2f;
#pragma unroll
    for (int i2 = 0; i2 < 4; ++i2) {
      a1f.u[i2] = Au[arow + hb + i2];
      a2f.u[i2] = A2u[arow + hb + i2];
    }
#pragma unroll
    for (int t2 = 0; t2 < 2; ++t2) {
      int n = t2 * 16 + ln;
      int baseT = n * 256 + (hb ^ ((n & 15) << 2));
      F8 bf;
#pragma unroll
      for (int i2 = 0; i2 < 4; ++i2) bf.u[i2] = xlsT[baseT + i2];
      acc1[t2] = __builtin_amdgcn_mfma_f32_16x16x32_bf16(a1f.s, bf.s, acc1[t2], 0, 0, 0);
      acc2[t2] = __builtin_amdgcn_mfma_f32_16x16x32_bf16(a2f.s, bf.s, acc2[t2], 0, 0, 0);
    }
  }
  int outb = bt * 16000;
#pragma unroll
  for (int t2 = 0; t2 < 2; ++t2) {
#pragma unroll
    for (int i2 = 0; i2 < 4; ++i2) {
      int r = rbase + q * 4 + i2;
      if (r < 500) {
        z1x[outb + r * 32 + t2 * 16 + ln] = acc1[t2][i2];
        z2x[outb + r * 32 + t2 * 16 + ln] = acc2[t2][i2];
      }
    }
  }
}

// ---------------- K3: MFMA fused attention: out = softmax(K K^T / sqrt(32)) @ V ----------------
__global__ __launch_bounds__(256, 2) void k_attn2(const float* __restrict__ keys,
                                                  const float* __restrict__ vals,
                                                  float* __restrict__ outp) {
  __shared__ u32 xls[8192];        // 512 rows x 16 u32 bf16-pairs, swizzled (32 KB)
  __shared__ u32 pch[4][272];      // per-wave P chunk: 16 x 17 u32 (4.25 KB)
  int tid = threadIdx.x, bt = blockIdx.x;
  const float* kb = keys + bt * 16000;
  for (int i = tid; i < 8192; i += 256) {
    int r = i >> 4, cu = i & 15;
    u32 u = 0;
    if (r < 500) {
      float2 g = *(const float2*)(kb + r * 32 + cu * 2);
      u = pk2(g.x, g.y);
    }
    xls[(r << 4) | (cu ^ (r & 15))] = u;
  }
  __syncthreads();
  int lane = tid & 63, wave = tid >> 6;
  int q = lane >> 4, ln = lane & 15;
  int rbase = blockIdx.y * 64 + wave * 16;
  union F8 { u32 u[4]; short8 s; };
  F8 af;
  {
    int r = rbase + ln;
#pragma unroll
    for (int i2 = 0; i2 < 4; ++i2)
      af.u[i2] = xls[(r << 4) | ((q * 4 + i2) ^ (r & 15))];
  }
  floatx4 acc[32];
#pragma unroll
  for (int ct = 0; ct < 32; ++ct) {
    int r2 = ct * 16 + ln;
    F8 bf;
#pragma unroll
    for (int i2 = 0; i2 < 4; ++i2)
      bf.u[i2] = xls[(r2 << 4) | ((q * 4 + i2) ^ (r2 & 15))];
    acc[ct] = __builtin_amdgcn_mfma_f32_16x16x32_bf16(af.s, bf.s,
              (floatx4){0.f, 0.f, 0.f, 0.f}, 0, 0, 0);
  }
  if (ln >= 4) {
#pragma unroll
    for (int i2 = 0; i2 < 4; ++i2) acc[31][i2] = -1e30f;
  }
  const float sc = 0.17677669529663687f;
  float inv[4];
#pragma unroll
  for (int i2 = 0; i2 < 4; ++i2) {
    float m = -1e30f;
#pragma unroll
    for (int ct = 0; ct < 32; ++ct) m = fmaxf(m, acc[ct][i2]);
#pragma unroll
    for (int d = 1; d < 16; d <<= 1) m = fmaxf(m, __shfl_xor(m, d));
    float s = 0.f;
#pragma unroll
    for (int ct = 0; ct < 32; ++ct) {
      float e = expf((acc[ct][i2] - m) * sc);
      acc[ct][i2] = e; s += e;
    }
#pragma unroll
    for (int d = 1; d < 16; d <<= 1) s += __shfl_xor(s, d);
    inv[i2] = 1.f / s;
  }
  const float* vb = vals + bt * 16000;
  floatx4 zacc[2] = {{0.f,0.f,0.f,0.f},{0.f,0.f,0.f,0.f}};
  u32* myp = pch[wave];
  u16* pw = (u16*)myp;
  for (int c2 = 0; c2 < 16; ++c2) {
#pragma unroll
    for (int t2 = 0; t2 < 2; ++t2) {
      int ct = c2 * 2 + t2;
#pragma unroll
      for (int i2 = 0; i2 < 4; ++i2)
        pw[(q * 4 + i2) * 34 + t2 * 16 + ln] = f2b(acc[ct][i2] * inv[i2]);
    }
    __syncthreads();
    F8 pa;
#pragma unroll
    for (int i2 = 0; i2 < 4; ++i2) pa.u[i2] = myp[ln * 17 + q * 4 + i2];
    int k0 = c2 * 32 + q * 8;
#pragma unroll
    for (int t2 = 0; t2 < 2; ++t2) {
      int n = t2 * 16 + ln;
      short8 bs;
#pragma unroll
      for (int j = 0; j < 8; ++j) {
        float v = vb[(k0 + j) * 32 + n];
        bs[j] = (short)(__float_as_uint(v) >> 16);
      }
      zacc[t2] = __builtin_amdgcn_mfma_f32_16x16x32_bf16(pa.s, bs, zacc[t2], 0, 0, 0);
    }
    __syncthreads();
  }
  int outb = bt * 16000;
#pragma unroll
  for (int t2 = 0; t2 < 2; ++t2) {
#pragma unroll
    for (int i2 = 0; i2 < 4; ++i2) {
      int r = rbase + q * 4 + i2;
      if (r < 500) outp[outb + r * 32 + t2 * 16 + ln] = zacc[t2][i2];
    }
  }
}

// ---------------- K4: MFMA mlp + gate + fused ct1 -> g2 ----------------
__global__ __launch_bounds__(256, 2) void k_gate(
    const float* __restrict__ h3x, const float* __restrict__ z1x, const float* __restrict__ z2x,
    const float* __restrict__ z3x, const float* __restrict__ z4x,
    const u32* __restrict__ WBq, const float* __restrict__ mlpB,
    const float* __restrict__ ct1W, const float* __restrict__ ct1B,
    float* __restrict__ g2w)
{
  __shared__ u32 wlds[5120];       // 20 KB: 20 B-frags x 64 lanes x 4 u32
  int tid = threadIdx.x;
  for (int i = tid; i < 5120; i += 256) wlds[i] = WBq[i];
  __syncthreads();
  int lane = tid & 63, wave = tid >> 6;
  int q = lane >> 4, ln = lane & 15;
  int b = blockIdx.y;
  int n0 = blockIdx.x * 32 + wave * 8;
  int nA = n0 + (ln & 7);          // A-row n for this lane
  int tAb = ln >> 3;               // A-row t_local (0/1)
  int nD = n0 + (q & 1) * 4;       // D-row n base (n = nD + i)
  int tDb = q >> 1;                // D-row t_local
  float g2a[4][2][6];
#pragma unroll
  for (int i = 0; i < 4; ++i)
#pragma unroll
    for (int ch = 0; ch < 2; ++ch)
#pragma unroll
      for (int s = 0; s < 6; ++s) g2a[i][ch][s] = 0.f;
  float bias[4];
#pragma unroll
  for (int ct = 0; ct < 4; ++ct) bias[ct] = mlpB[ct * 16 + ln];
  union F8 { u32 u[4]; short8 s; };
  for (int tile = 0; tile < 5; ++tile) {
    int tA = tile * 2 + tAb;
    int offA = (((b * 10 + tA) * 500) + nA) * 32 + q * 8;
    floatx4 acc[4];
#pragma unroll
    for (int ct = 0; ct < 4; ++ct) acc[ct] = (floatx4){bias[ct], bias[ct], bias[ct], bias[ct]};
#pragma unroll
    for (int kt = 0; kt < 5; ++kt) {
      const float* sp = kt == 0 ? h3x : kt == 1 ? z1x : kt == 2 ? z2x : kt == 3 ? z3x : z4x;
      float4 a0 = *(const float4*)(sp + offA);
      float4 a1 = *(const float4*)(sp + offA + 4);
      F8 af;
      af.u[0] = cvtpk(a0.x, a0.y);
      af.u[1] = cvtpk(a0.z, a0.w);
      af.u[2] = cvtpk(a1.x, a1.y);
      af.u[3] = cvtpk(a1.z, a1.w);
#pragma unroll
      for (int ct = 0; ct < 4; ++ct) {
        F8 bfr;
        const u32* wp = wlds + (((kt * 4 + ct) << 6) + lane) * 4;
#pragma unroll
        for (int i2 = 0; i2 < 4; ++i2) bfr.u[i2] = wp[i2];
        acc[ct] = __builtin_amdgcn_mfma_f32_16x16x32_bf16(af.s, bfr.s, acc[ct], 0, 0, 0);
      }
    }
    int tD = tile * 2 + tDb;
    float c6[6];
#pragma unroll
    for (int s = 0; s < 6; ++s) c6[s] = ct1W[s * 10 + tD];
#pragma unroll
    for (int i = 0; i < 4; ++i) {
      float e0 = __expf(2.f * acc[0][i]);
      float g0 = ((e0 - 1.f) / (e0 + 1.f)) * (1.f / (1.f + __expf(-acc[2][i])));
      float e1 = __expf(2.f * acc[1][i]);
      float g1 = ((e1 - 1.f) / (e1 + 1.f)) * (1.f / (1.f + __expf(-acc[3][i])));
#pragma unroll
      for (int s = 0; s < 6; ++s) {
        g2a[i][0][s] += g0 * c6[s];
        g2a[i][1][s] += g1 * c6[s];
      }
    }
  }
  // combine even-t (q=0,1) and odd-t (q=2,3) partial sums: lane pair = lane ^ 32
#pragma unroll
  for (int i = 0; i < 4; ++i)
#pragma unroll
    for (int ch = 0; ch < 2; ++ch)
#pragma unroll
      for (int s = 0; s < 6; ++s)
        g2a[i][ch][s] += __shfl_xor(g2a[i][ch][s], 32);
  if (q < 2) {
#pragma unroll
    for (int i = 0; i < 4; ++i) {
      int n = nD + i;
      if (n < 500) {
#pragma unroll
        for (int ch = 0; ch < 2; ++ch) {
          int c = ln + ch * 16;
          float* gp = g2w + ((b * 32 + c) * 500 + n) * 6;
#pragma unroll
          for (int s = 0; s < 6; ++s) gp[s] = g2a[i][ch][s] + ct1B[s];
        }
      }
    }
  }
}

// ---------------- K4b: f1 ----------------
__global__ __launch_bounds__(256) void k_f1n(const float* __restrict__ g2w,
                                             const float* __restrict__ tc1W,
                                             float* __restrict__ f1w) {
  int i = blockIdx.x * 256 + threadIdx.x;
  if (i >= 48000) return;
  int b = i / 3000, rem = i - b * 3000, s = rem / 500, n = rem - s * 500;
  float a = 0.f;
  for (int c = 0; c < 32; ++c) a += g2w[((b * 32 + c) * 500 + n) * 6 + s] * tc1W[c];
  f1w[(b * 6 + s) * 500 + n] = a;
}

// ---------------- K5a: f2 ----------------
__global__ __launch_bounds__(64) void k_f2(const float* __restrict__ g2w,
                                           const float* __restrict__ c2W, float* __restrict__ f2w) {
  int b = blockIdx.x >> 5, c = blockIdx.x & 31, lane = threadIdx.x;
  float acc[6];
#pragma unroll
  for (int t = 0; t < 6; ++t) acc[t] = 0.f;
  for (int n = lane; n < 500; n += 64) {
    float w = c2W[n];
    const float* gp = g2w + ((b * 32 + c) * 500 + n) * 6;
#pragma unroll
    for (int t = 0; t < 6; ++t) acc[t] += w * gp[t];
  }
#pragma unroll
  for (int t = 0; t < 6; ++t)
    for (int off = 32; off; off >>= 1) acc[t] += __shfl_xor(acc[t], off);
  if (lane == 0) {
#pragma unroll
    for (int t = 0; t < 6; ++t) f2w[(b * 32 + c) * 6 + t] = acc[t];
  }
}

// ---------------- K5b: per-b TATT ----------------
__global__ __launch_bounds__(256) void k_tatt(
    const float* __restrict__ f1w, const float* __restrict__ tatw,
    const float* __restrict__ f2w, const float* __restrict__ tatb, const float* __restrict__ tatv,
    float* __restrict__ lg2w)
{
  __shared__ float mid[192];
  __shared__ float lgt[36];
  int b = blockIdx.x, tid = threadIdx.x;
  if (tid < 192) {
    int t = tid >> 5, c = tid & 31;
    float a = 0.f;
    const float* f1p = f1w + (b * 6 + t) * 500;
    for (int n = 0; n < 500; ++n) a += f1p[n] * tatw[n * 32 + c];
    mid[t * 32 + c] = a;
  }
  __syncthreads();
  if (tid < 36) {
    int t = tid / 6, s = tid - t * 6;
    float a = tatb[t * 6 + s];
    for (int c = 0; c < 32; ++c) a += mid[t * 32 + c] * f2w[(b * 32 + c) * 6 + s];
    lgt[t * 6 + s] = 1.f / (1.f + expf(-a));
  }
  __syncthreads();
  if (tid < 36) {
    int p = tid / 6, s = tid - p * 6;
    float a = 0.f;
#pragma unroll
    for (int t2 = 0; t2 < 6; ++t2) a += tatv[p * 6 + t2] * lgt[t2 * 6 + s];
    lg2w[(b * 6 + p) * 6 + s] = a;
  }
}

// ---------------- K5c: BN1 + softmax -> Tc ----------------
__global__ __launch_bounds__(128) void k_coefs(const float* __restrict__ lg2w,
    const float* __restrict__ bn1g, const float* __restrict__ bn1b, float* __restrict__ tcw) {
  __shared__ float mu[6], iv[6], gg[6], bb[6];
  int tid = threadIdx.x;
  if (tid < 6) {
    float s = 0.f, sq = 0.f;
    for (int b = 0; b < 16; ++b)
      for (int q = 0; q < 6; ++q) {
        float v = lg2w[(b * 6 + q) * 6 + tid];
        s += v; sq += v * v;
      }
    float m = s / 96.f;
    mu[tid] = m;
    iv[tid] = rsqrtf(sq / 96.f - m * m + 1e-5f);
    gg[tid] = bn1g[tid]; bb[tid] = bn1b[tid];
  }
  __syncthreads();
  for (int idx = tid; idx < 96; idx += 128) {
    int b = idx / 6, q = idx - b * 6;
    float v[6], mx = -1e30f;
#pragma unroll
    for (int l = 0; l < 6; ++l) {
      v[l] = (lg2w[(b * 6 + q) * 6 + l] - mu[l]) * iv[l] * gg[l] + bb[l];
      mx = fmaxf(mx, v[l]);
    }
    float tot = 0.f;
#pragma unroll
    for (int l = 0; l < 6; ++l) { v[l] = expf(v[l] - mx); tot += v[l]; }
    float inv = 1.f / tot;
#pragma unroll
    for (int l = 0; l < 6; ++l) tcw[(b * 6 + l) * 6 + q] = v[l] * inv;
  }
}

// ---------------- K6a: xo = leaky(g2@Tc)+res6, per-c sum/sumsq ----------------
__global__ __launch_bounds__(256) void k_xo(const float* __restrict__ g2w,
    const float* __restrict__ res6, const float* __restrict__ tcw,
    float* __restrict__ xow, float* __restrict__ stats) {
  __shared__ float Tcl[36];
  __shared__ float redS[32][8], redQ[32][8];
  int b = blockIdx.x, chunk = blockIdx.y, tid = threadIdx.x;
  if (tid < 36) Tcl[tid] = tcw[b * 36 + tid];
  __syncthreads();
  int c = tid & 31, sub = tid >> 5;
  int n0 = chunk * 50;
  float s = 0.f, sq = 0.f;
  for (int idx = sub; idx < 300; idx += 8) {
    int nl = idx / 6, q = idx - nl * 6;
    int n = n0 + nl;
    int base = ((b * 32 + c) * 500 + n) * 6;
    const float* gp = g2w + base;
    float xv = 0.f;
#pragma unroll
    for (int l = 0; l < 6; ++l) xv += gp[l] * Tcl[l * 6 + q];
    xv = xv > 0.f ? xv : 0.01f * xv;
    xv += res6[base + q];
    xow[base + q] = xv;
    s += xv; sq += xv * xv;
  }
  redS[c][sub] = s; redQ[c][sub] = sq;
  __syncthreads();
  if (sub == 0) {
    float ts = 0.f, tq = 0.f;
#pragma unroll
    for (int k = 0; k < 8; ++k) { ts += redS[c][k]; tq += redQ[c][k]; }
    atomicAdd(&stats[c], ts);
    atomicAdd(&stats[32 + c], tq);
  }
}

// ---------------- K6b: BN2 normalize -> FP32 out ----------------
__global__ __launch_bounds__(256) void k_out(const float* __restrict__ xow,
    const float* __restrict__ stats, const float* __restrict__ g2c, const float* __restrict__ b2c,
    float* __restrict__ out) {
  int base = (blockIdx.x * 256 + threadIdx.x) * 4;
#pragma unroll
  for (int k = 0; k < 4; ++k) {
    int i = base + k;
    int c = (i / 3000) & 31;
    float m = stats[c] * (1.f / 48000.f);
    float var = stats[32 + c] * (1.f / 48000.f) - m * m;
    out[i] = (xow[i] - m) * rsqrtf(var + 1e-5f) * g2c[c] + b2c[c];
  }
}

extern "C" void kernel_launch(void* const* d_in, const int* in_sizes, int n_in,
                              void* d_out, int out_size, void* d_ws, size_t ws_size,
                              hipStream_t stream)
{
  (void)in_sizes; (void)out_size;

  float* ws = (float*)d_ws;
  float* Af   = ws;                 // 250,000
  float* Wf   = Af + 250000;        // 65,536 (65,322 used)
  float* A2   = Wf + 65536;         // 250,000 (unused; layout kept)
  float* h3x  = A2 + 250000;        // 2,560,000 (B,T,N,32)
  float* z1x  = h3x + 2560000;
  float* z2x  = z1x + 2560000;
  float* z3x  = z2x + 2560000;
  float* z4x  = z3x + 2560000;
  float* res6 = z4x + 2560000;      // 1,536,000
  float* g2w  = res6 + 1536000;     // 1,536,000
  float* f1w  = g2w + 1536000;      // 48,000
  float* f2w  = f1w + 48000;        // 3,072
  float* lg2w = f2w + 3072;         // 576
  float* tcw  = lg2w + 576;         // 576
  float* stats= tcw + 576;          // 64
  int*   dtf  = (int*)(stats + 64); // 1 int
  float* xf   = z4x;                // x fp32 overlay: dead after k_front3, before k_attn2#2
  float* xow  = z1x;                // reuse z1 region after k_gate
  u16*   Abf  = (u16*)g2w;          // 512x512 bf16 A pack (g2w region dead until k_gate)
  u16*   A2bf = (u16*)(g2w + 131072); // 512x512 bf16 A2 pack
  float* WTp  = g2w + 262144;       // 11,744 folded-weight pack (dead before k_gate)
  u16*   WBu  = (u16*)f1w;          // 10,240 u16 mlpW B-frag pack (f1w region dead until k_f1n)
  if (ws_size < (size_t)16489952 * sizeof(float)) return;  // workspace guard

  // converted-weight offsets inside Wf (cumulative over dict inputs 2..28)
  const float* c1B  = Wf + 1024;
  const float* mlpB = Wf + 48512;
  const float* ct1W = Wf + 48576;
  const float* ct1B = Wf + 48636;
  const float* tc1W = Wf + 48642;
  const float* tc2W = Wf + 48674;
  const float* tatw = Wf + 49174;
  const float* tatb = Wf + 65174;
  const float* tatv = Wf + 65210;
  const float* bn1g = Wf + 65246;
  const float* bn1b = Wf + 65252;
  const float* bn2g = Wf + 65258;
  const float* bn2b = Wf + 65290;

  Ptrs ps;
  for (int i = 0; i < 29; ++i) ps.p[i] = (i < n_in) ? d_in[i] : d_in[0];

  hipMemsetAsync(stats, 0, 64 * sizeof(float), stream);
  k_resolve<<<dim3(1),     64, 0, stream>>>(ps.p[25], dtf);
  k_cvt  <<<dim3(1232),    256, 0, stream>>>(ps, dtf, Af, Wf);
  k_cvtx <<<dim3(10000),   256, 0, stream>>>(ps.p[0], dtf, xf);
  k_wprep<<<dim3(86),      256, 0, stream>>>(Wf, WTp, WBu);
  k_pk   <<<dim3(1024),    256, 0, stream>>>(Af, Abf);
  k_a2m  <<<dim3(16, 8),   256, 0, stream>>>(Abf, A2bf);
  k_front3<<<dim3(2000),   256, 0, stream>>>(xf, WTp, c1B, h3x, res6);
  k_z12m <<<dim3(160, 8),  256, 0, stream>>>(h3x, Abf, A2bf, z1x, z2x);
  k_attn2<<<dim3(160, 8),  256, 0, stream>>>(h3x, h3x, z3x);
  k_attn2<<<dim3(160, 8),  256, 0, stream>>>(h3x, z3x, z4x);
  k_gate <<<dim3(16, 16),  256, 0, stream>>>(h3x, z1x, z2x, z3x, z4x,
                                             (const u32*)WBu, mlpB, ct1W, ct1B, g2w);
  k_f1n  <<<dim3(188),     256, 0, stream>>>(g2w, tc1W, f1w);
  k_f2   <<<dim3(512),      64, 0, stream>>>(g2w, tc2W, f2w);
  k_tatt <<<dim3(16),      256, 0, stream>>>(f1w, tatw, f2w, tatb, tatv, lg2w);
  k_coefs<<<dim3(1),       128, 0, stream>>>(lg2w, bn1g, bn1b, tcw);
  k_xo   <<<dim3(16, 10),  256, 0, stream>>>(g2w, res6, tcw, xow, stats);
  k_out  <<<dim3(1500),    256, 0, stream>>>(xow, stats, bn2g, bn2b, (float*)d_out);
}